// Round 6
// baseline (182.632 us; speedup 1.0000x reference)
//
#include <hip/hip_runtime.h>
#include <hip/hip_bf16.h>

typedef short short8 __attribute__((ext_vector_type(8)));
typedef short short4v __attribute__((ext_vector_type(4)));
typedef float f32x4 __attribute__((ext_vector_type(4)));
typedef __bf16 bf16x8 __attribute__((ext_vector_type(8)));

// ---------------- 8-wave single-barrier double-buffered GEMM (Bt form) -----
template <int ROWS>
__device__ __forceinline__ void stage2(const __hip_bfloat16* __restrict__ g,
                                       int ld, short* lds, int t) {
    const int w = t >> 6;
    const int lane = t & 63;
#pragma unroll
    for (int i = 0; i < ROWS / 64; ++i) {    // ROWS*8 chunks / 512 threads
        const int cb = i * 512 + w * 64;     // wave-uniform chunk base
        const int c = cb + lane;
        const int row = c >> 3;
        const int kc = (c & 7) ^ (row & 7);  // swizzled source k-chunk
        __builtin_amdgcn_global_load_lds((const void*)(g + (long)row * ld + kc * 8),
                                         (void*)(lds + cb * 8), 16, 0, 0);
    }
}

template <int BMt, int BNt, int WR, int WC, int ACT_TANH, int STORE_BF16>
__global__ __launch_bounds__(512, 2) void gemm_bt2_kernel(
    const __hip_bfloat16* __restrict__ A, long sA, int lda,
    const __hip_bfloat16* __restrict__ Bt, long sB, int ldb,
    void* __restrict__ Cptr, long sC, int ldc,
    const float* __restrict__ bias, int K) {
    constexpr int MR = BMt / (WR * 16);
    constexpr int NR = BNt / (WC * 16);
    __shared__ __align__(16) short sm[2][(BMt + BNt) * 64];

    int bx = blockIdx.x, by = blockIdx.y, bz = blockIdx.z;
    {   // T1 bijective XCD swizzle (nwg % 8 == 0)
        const int nx = gridDim.x, ny = gridDim.y;
        const int nwg = nx * ny * gridDim.z;
        const int lin = bx + nx * (by + ny * bz);
        const int swz = (lin & 7) * (nwg >> 3) + (lin >> 3);
        bx = swz % nx;
        const int r = swz / nx;
        by = r % ny;
        bz = r / ny;
    }

    const int t = threadIdx.x;
    const int w = t >> 6, lane = t & 63;
    const int wm = w / WC, wn = w % WC;
    const int fr = lane & 15, quad = lane >> 4;

    const __hip_bfloat16* Ab = A + bz * sA + (long)by * BMt * lda;
    const __hip_bfloat16* Bb = Bt + bz * sB + (long)bx * BNt * ldb;

    f32x4 acc[MR][NR] = {};

    const int nk = K / 64;
    stage2<BMt>(Ab, lda, &sm[0][0], t);
    stage2<BNt>(Bb, ldb, &sm[0][BMt * 64], t);
    __syncthreads();

    int cur = 0;
    for (int kt = 0; kt < nk; ++kt) {
        if (kt + 1 < nk) {
            stage2<BMt>(Ab + (kt + 1) * 64, lda, &sm[cur ^ 1][0], t);
            stage2<BNt>(Bb + (kt + 1) * 64, ldb, &sm[cur ^ 1][BMt * 64], t);
        }
        const short* At = &sm[cur][0];
        const short* Bts = &sm[cur][BMt * 64];
#pragma unroll
        for (int ks = 0; ks < 2; ++ks) {
            bf16x8 af[MR], bfv[NR];
            const int kc = ks * 4 + quad;
#pragma unroll
            for (int m = 0; m < MR; ++m) {
                const int row = wm * (MR * 16) + m * 16 + fr;
                const int chunk = row * 8 + (kc ^ (row & 7));
                af[m] = *(const bf16x8*)(const void*)(At + chunk * 8);
            }
#pragma unroll
            for (int n = 0; n < NR; ++n) {
                const int row = wn * (NR * 16) + n * 16 + fr;
                const int chunk = row * 8 + (kc ^ (row & 7));
                bfv[n] = *(const bf16x8*)(const void*)(Bts + chunk * 8);
            }
#pragma unroll
            for (int m = 0; m < MR; ++m)
#pragma unroll
                for (int n = 0; n < NR; ++n)
                    acc[m][n] = __builtin_amdgcn_mfma_f32_16x16x32_bf16(
                        af[m], bfv[n], acc[m][n], 0, 0, 0);
        }
        if (kt + 1 < nk) __syncthreads();
        cur ^= 1;
    }

    const long rowBase = (long)by * BMt + wm * (MR * 16);
    const int colBase = bx * BNt + wn * (NR * 16);
#pragma unroll
    for (int m = 0; m < MR; ++m) {
#pragma unroll
        for (int n = 0; n < NR; ++n) {
            const int col = colBase + n * 16 + fr;
            const float bv = ACT_TANH ? bias[col] : 0.f;
#pragma unroll
            for (int j = 0; j < 4; ++j) {
                const long row = rowBase + m * 16 + quad * 4 + j;
                float v = acc[m][n][j];
                if (ACT_TANH) v = tanhf(v + bv);
                if (STORE_BF16)
                    ((__hip_bfloat16*)Cptr)[bz * sC + row * ldc + col] =
                        __float2bfloat16(v);
                else
                    ((float*)Cptr)[bz * sC + row * ldc + col] = v;
            }
        }
    }
}

// ---------------- pure streaming cvt: X f32 -> Xbf bf16 --------------------
__global__ __launch_bounds__(256) void cvt_x_kernel(const float* __restrict__ in,
                                                    __hip_bfloat16* __restrict__ out,
                                                    long n) {
    const long i = ((long)blockIdx.x * 256 + threadIdx.x) * 16;
    if (i >= n) return;
    const float4 a = *(const float4*)(in + i);
    const float4 b = *(const float4*)(in + i + 4);
    const float4 c = *(const float4*)(in + i + 8);
    const float4 d = *(const float4*)(in + i + 12);
    __hip_bfloat16 tmp[16] __attribute__((aligned(16)));
    tmp[0] = __float2bfloat16(a.x);  tmp[1] = __float2bfloat16(a.y);
    tmp[2] = __float2bfloat16(a.z);  tmp[3] = __float2bfloat16(a.w);
    tmp[4] = __float2bfloat16(b.x);  tmp[5] = __float2bfloat16(b.y);
    tmp[6] = __float2bfloat16(b.z);  tmp[7] = __float2bfloat16(b.w);
    tmp[8] = __float2bfloat16(c.x);  tmp[9] = __float2bfloat16(c.y);
    tmp[10] = __float2bfloat16(c.z); tmp[11] = __float2bfloat16(c.w);
    tmp[12] = __float2bfloat16(d.x); tmp[13] = __float2bfloat16(d.y);
    tmp[14] = __float2bfloat16(d.z); tmp[15] = __float2bfloat16(d.w);
    *(short8*)(void*)(out + i) = *(short8*)(void*)&tmp[0];
    *(short8*)(void*)(out + i + 8) = *(short8*)(void*)&tmp[8];
}

// ---------------- bf16 transpose: Xbf [b][512][1024] -> Xt [b][1024][512] --
// 128t x 128h tile per block, 256 threads. LDS granule-XOR swizzle:
// granule (t, hc) stored at row t, col-granule hc ^ (t&15). Phase-2 16-lane
// groups then read only 2 distinct addresses on different banks (broadcast).
__global__ __launch_bounds__(256) void transpose_bf16_kernel(
    const __hip_bfloat16* __restrict__ in, __hip_bfloat16* __restrict__ outp) {
    __shared__ __align__(16) short tile[128 * 128];  // 32 KB
    const int b = blockIdx.z;
    const int h0 = blockIdx.x * 128, t0 = blockIdx.y * 128;
    const int tid = threadIdx.x;
    const __hip_bfloat16* ib = in + ((long)(b * 512 + t0)) * 1024 + h0;
    __hip_bfloat16* ob = outp + ((long)(b * 1024 + h0)) * 512 + t0;
#pragma unroll
    for (int p = 0; p < 8; ++p) {
        const int id = p * 256 + tid;
        const int tl = id >> 4;   // 0..127 (t within tile)
        const int hc = id & 15;   // h-granule 0..15
        const short8 v = *(const short8*)(const void*)(ib + (long)tl * 1024 + hc * 8);
        *(short8*)(void*)&tile[tl * 128 + ((hc ^ (tl & 15)) * 8)] = v;
    }
    __syncthreads();
#pragma unroll
    for (int p = 0; p < 8; ++p) {
        const int id = p * 256 + tid;
        const int tc = id & 15;   // t-granule 0..15
        const int hl = id >> 4;   // 0..127 (h within tile)
        __hip_bfloat16 tmp[8] __attribute__((aligned(16)));
#pragma unroll
        for (int j = 0; j < 8; ++j) {
            const int t = tc * 8 + j;
            tmp[j] = ((const __hip_bfloat16*)(const void*)tile)[t * 128 + (((hl >> 3) ^ (t & 15)) * 8) + (hl & 7)];
        }
        *(short8*)(void*)(ob + (long)hl * 512 + tc * 8) = *(short8*)(void*)tmp;
    }
}

// naive small transpose+convert: in [R][C] f32 -> out [C][R] bf16
__global__ __launch_bounds__(256) void transpose_cvt_kernel(const float* __restrict__ in,
                                                            __hip_bfloat16* __restrict__ out,
                                                            int R, int C) {
    const int o = blockIdx.x * 256 + threadIdx.x;
    if (o >= R * C) return;
    const int c = o / R;
    const int r = o - c * R;
    out[o] = __float2bfloat16(in[(long)r * C + c]);
}

// Fused scores+masked-softmax: per block, 64 query rows x full 512 key cols.
__global__ __launch_bounds__(512) void score_softmax_kernel(
    const __hip_bfloat16* __restrict__ Aa,  // alpha [32768][256]
    const __hip_bfloat16* __restrict__ Ut,  // [512][256]
    __hip_bfloat16* __restrict__ P,         // [32768][512]
    const int* __restrict__ sen) {
    __shared__ __align__(16) short At[64 * 64];
    __shared__ __align__(16) short Bts[512 * 64];
    __shared__ float red[2][64][9];

    const int t = threadIdx.x;
    const int w = t >> 6, lane = t & 63;
    const int fr = lane & 15, quad = lane >> 4;
    const long row0 = (long)blockIdx.x * 64;
    const __hip_bfloat16* Ab = Aa + row0 * 256;

    f32x4 acc[4][4] = {};

    for (int kt = 0; kt < 4; ++kt) {  // K = 256, BK = 64
        if (kt) __syncthreads();
        {
            const int cb = w * 64;
            const int c = cb + lane;
            const int row = c >> 3, kc = (c & 7) ^ (row & 7);
            __builtin_amdgcn_global_load_lds(
                (const void*)(Ab + (long)row * 256 + kt * 64 + kc * 8),
                (void*)(At + cb * 8), 16, 0, 0);
        }
#pragma unroll
        for (int i = 0; i < 8; ++i) {
            const int cb = i * 512 + w * 64;
            const int c = cb + lane;
            const int row = c >> 3, kc = (c & 7) ^ (row & 7);
            __builtin_amdgcn_global_load_lds(
                (const void*)(Ut + (long)row * 256 + kt * 64 + kc * 8),
                (void*)(Bts + cb * 8), 16, 0, 0);
        }
        __syncthreads();
#pragma unroll
        for (int ks = 0; ks < 2; ++ks) {
            bf16x8 af[4], bfv[4];
            const int kc = ks * 4 + quad;
#pragma unroll
            for (int m = 0; m < 4; ++m) {
                const int row = m * 16 + fr;
                const int chunk = row * 8 + (kc ^ (row & 7));
                af[m] = *(const bf16x8*)(const void*)(At + chunk * 8);
            }
#pragma unroll
            for (int n = 0; n < 4; ++n) {
                const int row = w * 64 + n * 16 + fr;
                const int chunk = row * 8 + (kc ^ (row & 7));
                bfv[n] = *(const bf16x8*)(const void*)(Bts + chunk * 8);
            }
#pragma unroll
            for (int m = 0; m < 4; ++m)
#pragma unroll
                for (int n = 0; n < 4; ++n)
                    acc[m][n] = __builtin_amdgcn_mfma_f32_16x16x32_bf16(
                        af[m], bfv[n], acc[m][n], 0, 0, 0);
        }
    }
    __syncthreads();

    const int L = sen[row0 >> 9];
    bool valid[4];
#pragma unroll
    for (int n = 0; n < 4; ++n) valid[n] = (w * 64 + n * 16 + fr) < L;

    float mx[4][4];
#pragma unroll
    for (int m = 0; m < 4; ++m)
#pragma unroll
        for (int j = 0; j < 4; ++j) {
            float v = -3.0e38f;
#pragma unroll
            for (int n = 0; n < 4; ++n)
                if (valid[n]) v = fmaxf(v, acc[m][n][j]);
#pragma unroll
            for (int off = 8; off >= 1; off >>= 1) v = fmaxf(v, __shfl_xor(v, off, 64));
            mx[m][j] = v;
        }
    if (fr == 0) {
#pragma unroll
        for (int m = 0; m < 4; ++m)
#pragma unroll
            for (int j = 0; j < 4; ++j) red[0][m * 16 + quad * 4 + j][w] = mx[m][j];
    }
    __syncthreads();
    float rmax[4][4];
#pragma unroll
    for (int m = 0; m < 4; ++m)
#pragma unroll
        for (int j = 0; j < 4; ++j) {
            const int row = m * 16 + quad * 4 + j;
            float v = red[0][row][0];
#pragma unroll
            for (int ww = 1; ww < 8; ++ww) v = fmaxf(v, red[0][row][ww]);
            rmax[m][j] = v;
        }

    float sum[4][4];
#pragma unroll
    for (int m = 0; m < 4; ++m)
#pragma unroll
        for (int j = 0; j < 4; ++j) {
            float s = 0.f;
#pragma unroll
            for (int n = 0; n < 4; ++n) {
                float e = valid[n] ? __expf(acc[m][n][j] - rmax[m][j]) : 0.f;
                acc[m][n][j] = e;
                s += e;
            }
#pragma unroll
            for (int off = 8; off >= 1; off >>= 1) s += __shfl_xor(s, off, 64);
            sum[m][j] = s;
        }
    if (fr == 0) {
#pragma unroll
        for (int m = 0; m < 4; ++m)
#pragma unroll
            for (int j = 0; j < 4; ++j) red[1][m * 16 + quad * 4 + j][w] = sum[m][j];
    }
    __syncthreads();
#pragma unroll
    for (int m = 0; m < 4; ++m)
#pragma unroll
        for (int j = 0; j < 4; ++j) {
            const int row = m * 16 + quad * 4 + j;
            float s = 0.f;
#pragma unroll
            for (int ww = 0; ww < 8; ++ww) s += red[1][row][ww];
            const float inv = 1.f / s;
#pragma unroll
            for (int n = 0; n < 4; ++n)
                P[(row0 + row) * 512 + w * 64 + n * 16 + fr] =
                    __float2bfloat16(acc[m][n][j] * inv);
        }
}

extern "C" void kernel_launch(void* const* d_in, const int* in_sizes, int n_in,
                              void* d_out, int out_size, void* d_ws, size_t ws_size,
                              hipStream_t stream) {
    const float* X = (const float*)d_in[0];
    const int* sen = (const int*)d_in[1];
    const float* W = (const float*)d_in[2];
    const float* bias = (const float*)d_in[3];
    const float* U = (const float*)d_in[4];
    float* out = (float*)d_out;

    const int B = 64, T = 512, H = 1024, A = 256;
    const long M = (long)B * T;  // 32768

    // workspace: Xt (64Mi) | P (32Mi) | Wt (0.5Mi) | Ut (0.25Mi)
    char* ws = (char*)d_ws;
    __hip_bfloat16* Xt = (__hip_bfloat16*)ws;
    __hip_bfloat16* Pbf = (__hip_bfloat16*)(ws + M * H * 2);
    __hip_bfloat16* Wt = (__hip_bfloat16*)(ws + M * H * 2 + M * T * 2);
    __hip_bfloat16* Ut = (__hip_bfloat16*)((char*)Wt + (long)H * A * 2);

    // d_out doubles as scratch: Xbf bf16 in [0,64Mi), alpha bf16 at [64Mi,80Mi).
    // Both are dead before the final GEMM overwrites d_out with Z.
    __hip_bfloat16* Xbf = (__hip_bfloat16*)d_out;
    __hip_bfloat16* alpha = (__hip_bfloat16*)((char*)d_out + M * H * 2);

    // 1. X -> bf16 (pure streaming)
    cvt_x_kernel<<<(int)(M * H / 16 / 256), 256, 0, stream>>>(X, Xbf, M * H);
    // 1b. Xbf -> Xt (bf16 transpose, swizzled LDS)
    transpose_bf16_kernel<<<dim3(H / 128, T / 128, B), 256, 0, stream>>>(Xbf, Xt);
    // 2. W^T [A][H], U^T [T][A]
    transpose_cvt_kernel<<<(H * A) / 256, 256, 0, stream>>>(W, Wt, H, A);
    transpose_cvt_kernel<<<(A * T) / 256, 256, 0, stream>>>(U, Ut, A, T);
    // 3. alpha = tanh(X*W + b)  [32768,256]  256x128 tile -> 256 wgs
    gemm_bt2_kernel<256, 128, 4, 2, 1, 1><<<dim3(A / 128, (int)(M / 256), 1), 512, 0, stream>>>(
        Xbf, 0, H, Wt, 0, H, (void*)alpha, 0, A, bias, H);
    // 4+5. P = softmax(alpha * U^T, mask) fused, bf16
    score_softmax_kernel<<<(int)(M / 64), 512, 0, stream>>>(alpha, Ut, Pbf, sen);
    // 6. Z = P * X  (batched; Bt = Xt)  256x256 tile -> 512 wgs
    gemm_bt2_kernel<256, 256, 2, 4, 0, 0><<<dim3(H / 256, T / 256, B), 512, 0, stream>>>(
        Pbf, (long)T * T, T, Xt, (long)H * T, T, (void*)out, (long)T * H, H,
        nullptr, T);
}

// Round 7
// 174.507 us; speedup vs baseline: 1.0466x; 1.0466x over previous
//
#include <hip/hip_runtime.h>
#include <hip/hip_bf16.h>

typedef short short8 __attribute__((ext_vector_type(8)));
typedef short short4v __attribute__((ext_vector_type(4)));
typedef float f32x4 __attribute__((ext_vector_type(4)));
typedef __bf16 bf16x8 __attribute__((ext_vector_type(8)));

// ---------------- 8-wave single-barrier double-buffered GEMM (Bt form) -----
template <int ROWS>
__device__ __forceinline__ void stage2(const __hip_bfloat16* __restrict__ g,
                                       int ld, short* lds, int t) {
    const int w = t >> 6;
    const int lane = t & 63;
#pragma unroll
    for (int i = 0; i < ROWS / 64; ++i) {    // ROWS*8 chunks / 512 threads
        const int cb = i * 512 + w * 64;     // wave-uniform chunk base
        const int c = cb + lane;
        const int row = c >> 3;
        const int kc = (c & 7) ^ (row & 7);  // swizzled source k-chunk
        __builtin_amdgcn_global_load_lds((const void*)(g + (long)row * ld + kc * 8),
                                         (void*)(lds + cb * 8), 16, 0, 0);
    }
}

template <int BMt, int BNt, int WR, int WC, int ACT_TANH, int STORE_BF16>
__global__ __launch_bounds__(512, 2) void gemm_bt2_kernel(
    const __hip_bfloat16* __restrict__ A, long sA, int lda,
    const __hip_bfloat16* __restrict__ Bt, long sB, int ldb,
    void* __restrict__ Cptr, long sC, int ldc,
    const float* __restrict__ bias, int K) {
    constexpr int MR = BMt / (WR * 16);
    constexpr int NR = BNt / (WC * 16);
    __shared__ __align__(16) short sm[2][(BMt + BNt) * 64];

    int bx = blockIdx.x, by = blockIdx.y, bz = blockIdx.z;
    {   // T1 bijective XCD swizzle (nwg % 8 == 0)
        const int nx = gridDim.x, ny = gridDim.y;
        const int nwg = nx * ny * gridDim.z;
        const int lin = bx + nx * (by + ny * bz);
        const int swz = (lin & 7) * (nwg >> 3) + (lin >> 3);
        bx = swz % nx;
        const int r = swz / nx;
        by = r % ny;
        bz = r / ny;
    }

    const int t = threadIdx.x;
    const int w = t >> 6, lane = t & 63;
    const int wm = w / WC, wn = w % WC;
    const int fr = lane & 15, quad = lane >> 4;

    const __hip_bfloat16* Ab = A + bz * sA + (long)by * BMt * lda;
    const __hip_bfloat16* Bb = Bt + bz * sB + (long)bx * BNt * ldb;

    f32x4 acc[MR][NR] = {};

    const int nk = K / 64;
    stage2<BMt>(Ab, lda, &sm[0][0], t);
    stage2<BNt>(Bb, ldb, &sm[0][BMt * 64], t);
    __syncthreads();

    int cur = 0;
    for (int kt = 0; kt < nk; ++kt) {
        if (kt + 1 < nk) {
            stage2<BMt>(Ab + (kt + 1) * 64, lda, &sm[cur ^ 1][0], t);
            stage2<BNt>(Bb + (kt + 1) * 64, ldb, &sm[cur ^ 1][BMt * 64], t);
        }
        const short* At = &sm[cur][0];
        const short* Bts = &sm[cur][BMt * 64];
#pragma unroll
        for (int ks = 0; ks < 2; ++ks) {
            bf16x8 af[MR], bfv[NR];
            const int kc = ks * 4 + quad;
#pragma unroll
            for (int m = 0; m < MR; ++m) {
                const int row = wm * (MR * 16) + m * 16 + fr;
                const int chunk = row * 8 + (kc ^ (row & 7));
                af[m] = *(const bf16x8*)(const void*)(At + chunk * 8);
            }
#pragma unroll
            for (int n = 0; n < NR; ++n) {
                const int row = wn * (NR * 16) + n * 16 + fr;
                const int chunk = row * 8 + (kc ^ (row & 7));
                bfv[n] = *(const bf16x8*)(const void*)(Bts + chunk * 8);
            }
#pragma unroll
            for (int m = 0; m < MR; ++m)
#pragma unroll
                for (int n = 0; n < NR; ++n)
                    acc[m][n] = __builtin_amdgcn_mfma_f32_16x16x32_bf16(
                        af[m], bfv[n], acc[m][n], 0, 0, 0);
        }
        if (kt + 1 < nk) __syncthreads();
        cur ^= 1;
    }

    const long rowBase = (long)by * BMt + wm * (MR * 16);
    const int colBase = bx * BNt + wn * (NR * 16);
#pragma unroll
    for (int m = 0; m < MR; ++m) {
#pragma unroll
        for (int n = 0; n < NR; ++n) {
            const int col = colBase + n * 16 + fr;
            const float bv = ACT_TANH ? bias[col] : 0.f;
#pragma unroll
            for (int j = 0; j < 4; ++j) {
                const long row = rowBase + m * 16 + quad * 4 + j;
                float v = acc[m][n][j];
                if (ACT_TANH) v = tanhf(v + bv);
                if (STORE_BF16)
                    ((__hip_bfloat16*)Cptr)[bz * sC + row * ldc + col] =
                        __float2bfloat16(v);
                else
                    ((float*)Cptr)[bz * sC + row * ldc + col] = v;
            }
        }
    }
}

// ---------------- transpose_x: X f32 [b][512][1024] -> Xt bf16 [b][h][t] ---
// Tile = FULL t (512) x 64 h per block, so every Xt row (1 KB) is written
// whole by one block (fixes cross-XCD partial-row DRAM thrash). LDS [512][66]
// bf16 (132 B row stride): phase-2 gather spreads 16 banks (~4-way). Chunked
// XCD swizzle: all 16 h-blocks of one batch share an XCD -> each 4 KB X row
// is fetched from HBM once and L2-shared.
__global__ __launch_bounds__(512) void transpose_x_kernel(
    const float* __restrict__ X, __hip_bfloat16* __restrict__ Xt) {
    __shared__ __align__(4) short tile[512 * 66];
    int bx = blockIdx.x, bz = blockIdx.y;  // grid (16, 64)
    {
        const int lin = bx + 16 * bz;                 // 0..1023
        const int swz = (lin & 7) * 128 + (lin >> 3); // chunked: 128/XCD
        bx = swz & 15;
        bz = swz >> 4;
    }
    const int tid = threadIdx.x;
    const float* Xb = X + ((long)bz * 512) * 1024 + bx * 64;
    __hip_bfloat16* ob = Xt + ((long)(bz * 1024 + bx * 64)) * 512;

    // phase 1: read 512 rows x 64 f32 (256B/row), cvt, store to LDS [t][h]
#pragma unroll
    for (int p = 0; p < 16; ++p) {
        const int c = p * 512 + tid;   // 8192 float4-chunks
        const int t = c >> 4;          // 0..511
        const int fc = c & 15;         // 0..15 (h-chunk of 4)
        const float4 v = *(const float4*)(Xb + (long)t * 1024 + fc * 4);
        __hip_bfloat16 h0 = __float2bfloat16(v.x), h1 = __float2bfloat16(v.y);
        __hip_bfloat16 h2 = __float2bfloat16(v.z), h3 = __float2bfloat16(v.w);
        const int w0 = (int)*(unsigned short*)&h0 | ((int)*(unsigned short*)&h1 << 16);
        const int w1 = (int)*(unsigned short*)&h2 | ((int)*(unsigned short*)&h3 << 16);
        int* dst = (int*)(void*)&tile[t * 66 + fc * 4];  // byte 132t+8fc, 4-aligned
        dst[0] = w0;
        dst[1] = w1;
    }
    __syncthreads();

    // phase 2: gather 8 t-consecutive bf16 per store, write FULL Xt rows.
    const int h = tid >> 3;      // 0..63
    const int cklo = tid & 7;
#pragma unroll
    for (int p = 0; p < 8; ++p) {
        const int ck = p * 8 + cklo;  // 0..63 (t-chunk of 8)
        short tmp[8] __attribute__((aligned(16)));
#pragma unroll
        for (int j = 0; j < 8; ++j) tmp[j] = tile[(8 * ck + j) * 66 + h];
        *(short8*)(void*)(ob + (long)h * 512 + ck * 8) = *(short8*)(void*)tmp;
    }
}

// ---------------- gemm_xw: alpha = tanh(X_f32 * Wt^T + b) ------------------
// BM=256(t) x BN=128(a) x BK=64(h), K=1024, 512 thr, waves 4x2, MR=NR=4.
// A-side reg-staged from f32 X (T14 split: load early, cvt+ds_write after
// MFMA); B-side (Wt bf16) via global_load_lds. X is L3-resident (just
// streamed by transpose_x), so the f32 re-read is cheap.
__global__ __launch_bounds__(512, 2) void gemm_xw_kernel(
    const float* __restrict__ Xf,           // [32768][1024]
    const __hip_bfloat16* __restrict__ Wt,  // [256][1024]
    __hip_bfloat16* __restrict__ alpha,     // [32768][256]
    const float* __restrict__ bias) {
    __shared__ __align__(16) short sm[2][24576];  // A 16384 | B 8192 shorts

    int bx = blockIdx.x, by = blockIdx.y;
    {   // T1 swizzle, nwg = 256
        const int nx = gridDim.x, ny = gridDim.y;
        const int nwg = nx * ny;
        const int lin = bx + nx * by;
        const int swz = (lin & 7) * (nwg >> 3) + (lin >> 3);
        bx = swz % nx;
        by = swz / nx;
    }

    const int t = threadIdx.x;
    const int w = t >> 6, lane = t & 63;
    const int wm = w >> 1, wn = w & 1;
    const int fr = lane & 15, quad = lane >> 4;

    const float* Ab = Xf + (long)by * 256 * 1024;
    const __hip_bfloat16* Bb = Wt + (long)bx * 128 * 1024;

    // A chunk assignment: chunk c holds (row=c>>3, kc=(c&7)^(row&7))
    int arow[4], akc[4];
#pragma unroll
    for (int i = 0; i < 4; ++i) {
        const int c = i * 512 + t;
        arow[i] = c >> 3;
        akc[i] = ((c & 7) ^ (arow[i] & 7)) * 8;
    }

    f32x4 acc[4][4] = {};
    float4 rA[4][2];

    // prologue: kt=0
#pragma unroll
    for (int i = 0; i < 4; ++i) {
        const float* src = Ab + (long)arow[i] * 1024 + akc[i];
        rA[i][0] = *(const float4*)(src);
        rA[i][1] = *(const float4*)(src + 4);
    }
    stage2<128>(Bb, 1024, &sm[0][16384], t);
#pragma unroll
    for (int i = 0; i < 4; ++i) {
        const int c = i * 512 + t;
        __hip_bfloat16 tmp[8] __attribute__((aligned(16)));
        tmp[0] = __float2bfloat16(rA[i][0].x); tmp[1] = __float2bfloat16(rA[i][0].y);
        tmp[2] = __float2bfloat16(rA[i][0].z); tmp[3] = __float2bfloat16(rA[i][0].w);
        tmp[4] = __float2bfloat16(rA[i][1].x); tmp[5] = __float2bfloat16(rA[i][1].y);
        tmp[6] = __float2bfloat16(rA[i][1].z); tmp[7] = __float2bfloat16(rA[i][1].w);
        *(short8*)(void*)&sm[0][c * 8] = *(short8*)(void*)tmp;
    }
    __syncthreads();

    int cur = 0;
    for (int kt = 0; kt < 16; ++kt) {
        const bool more = kt + 1 < 16;
        if (more) {  // issue next A loads + B stage BEFORE compute
#pragma unroll
            for (int i = 0; i < 4; ++i) {
                const float* src = Ab + (long)arow[i] * 1024 + (kt + 1) * 64 + akc[i];
                rA[i][0] = *(const float4*)(src);
                rA[i][1] = *(const float4*)(src + 4);
            }
            stage2<128>(Bb + (kt + 1) * 64, 1024, &sm[cur ^ 1][16384], t);
        }
        const short* At = &sm[cur][0];
        const short* Bts = &sm[cur][16384];
#pragma unroll
        for (int ks = 0; ks < 2; ++ks) {
            bf16x8 af[4], bfv[4];
            const int kc = ks * 4 + quad;
#pragma unroll
            for (int m = 0; m < 4; ++m) {
                const int row = wm * 64 + m * 16 + fr;
                const int chunk = row * 8 + (kc ^ (row & 7));
                af[m] = *(const bf16x8*)(const void*)(At + chunk * 8);
            }
#pragma unroll
            for (int n = 0; n < 4; ++n) {
                const int row = wn * 64 + n * 16 + fr;
                const int chunk = row * 8 + (kc ^ (row & 7));
                bfv[n] = *(const bf16x8*)(const void*)(Bts + chunk * 8);
            }
#pragma unroll
            for (int m = 0; m < 4; ++m)
#pragma unroll
                for (int n = 0; n < 4; ++n)
                    acc[m][n] = __builtin_amdgcn_mfma_f32_16x16x32_bf16(
                        af[m], bfv[n], acc[m][n], 0, 0, 0);
        }
        if (more) {  // cvt + LDS-write the prefetched A, then barrier
#pragma unroll
            for (int i = 0; i < 4; ++i) {
                const int c = i * 512 + t;
                __hip_bfloat16 tmp[8] __attribute__((aligned(16)));
                tmp[0] = __float2bfloat16(rA[i][0].x); tmp[1] = __float2bfloat16(rA[i][0].y);
                tmp[2] = __float2bfloat16(rA[i][0].z); tmp[3] = __float2bfloat16(rA[i][0].w);
                tmp[4] = __float2bfloat16(rA[i][1].x); tmp[5] = __float2bfloat16(rA[i][1].y);
                tmp[6] = __float2bfloat16(rA[i][1].z); tmp[7] = __float2bfloat16(rA[i][1].w);
                *(short8*)(void*)&sm[cur ^ 1][c * 8] = *(short8*)(void*)tmp;
            }
            __syncthreads();
        }
        cur ^= 1;
    }

    const long rowBase = (long)by * 256 + wm * 64;
    const int colBase = bx * 128 + wn * 64;
#pragma unroll
    for (int m = 0; m < 4; ++m) {
#pragma unroll
        for (int n = 0; n < 4; ++n) {
            const int col = colBase + n * 16 + fr;
            const float bv = bias[col];
#pragma unroll
            for (int j = 0; j < 4; ++j) {
                const long row = rowBase + m * 16 + quad * 4 + j;
                alpha[row * 256 + col] = __float2bfloat16(tanhf(acc[m][n][j] + bv));
            }
        }
    }
}

// naive small transpose+convert: in [R][C] f32 -> out [C][R] bf16
__global__ __launch_bounds__(256) void transpose_cvt_kernel(const float* __restrict__ in,
                                                            __hip_bfloat16* __restrict__ out,
                                                            int R, int C) {
    const int o = blockIdx.x * 256 + threadIdx.x;
    if (o >= R * C) return;
    const int c = o / R;
    const int r = o - c * R;
    out[o] = __float2bfloat16(in[(long)r * C + c]);
}

// Fused scores+masked-softmax: per block, 64 query rows x full 512 key cols.
__global__ __launch_bounds__(512) void score_softmax_kernel(
    const __hip_bfloat16* __restrict__ Aa,  // alpha [32768][256]
    const __hip_bfloat16* __restrict__ Ut,  // [512][256]
    __hip_bfloat16* __restrict__ P,         // [32768][512]
    const int* __restrict__ sen) {
    __shared__ __align__(16) short At[64 * 64];
    __shared__ __align__(16) short Bts[512 * 64];
    __shared__ float red[2][64][9];

    const int t = threadIdx.x;
    const int w = t >> 6, lane = t & 63;
    const int fr = lane & 15, quad = lane >> 4;
    const long row0 = (long)blockIdx.x * 64;
    const __hip_bfloat16* Ab = Aa + row0 * 256;

    f32x4 acc[4][4] = {};

    for (int kt = 0; kt < 4; ++kt) {  // K = 256, BK = 64
        if (kt) __syncthreads();
        {
            const int cb = w * 64;
            const int c = cb + lane;
            const int row = c >> 3, kc = (c & 7) ^ (row & 7);
            __builtin_amdgcn_global_load_lds(
                (const void*)(Ab + (long)row * 256 + kt * 64 + kc * 8),
                (void*)(At + cb * 8), 16, 0, 0);
        }
#pragma unroll
        for (int i = 0; i < 8; ++i) {
            const int cb = i * 512 + w * 64;
            const int c = cb + lane;
            const int row = c >> 3, kc = (c & 7) ^ (row & 7);
            __builtin_amdgcn_global_load_lds(
                (const void*)(Ut + (long)row * 256 + kt * 64 + kc * 8),
                (void*)(Bts + cb * 8), 16, 0, 0);
        }
        __syncthreads();
#pragma unroll
        for (int ks = 0; ks < 2; ++ks) {
            bf16x8 af[4], bfv[4];
            const int kc = ks * 4 + quad;
#pragma unroll
            for (int m = 0; m < 4; ++m) {
                const int row = m * 16 + fr;
                const int chunk = row * 8 + (kc ^ (row & 7));
                af[m] = *(const bf16x8*)(const void*)(At + chunk * 8);
            }
#pragma unroll
            for (int n = 0; n < 4; ++n) {
                const int row = w * 64 + n * 16 + fr;
                const int chunk = row * 8 + (kc ^ (row & 7));
                bfv[n] = *(const bf16x8*)(const void*)(Bts + chunk * 8);
            }
#pragma unroll
            for (int m = 0; m < 4; ++m)
#pragma unroll
                for (int n = 0; n < 4; ++n)
                    acc[m][n] = __builtin_amdgcn_mfma_f32_16x16x32_bf16(
                        af[m], bfv[n], acc[m][n], 0, 0, 0);
        }
    }
    __syncthreads();

    const int L = sen[row0 >> 9];
    bool valid[4];
#pragma unroll
    for (int n = 0; n < 4; ++n) valid[n] = (w * 64 + n * 16 + fr) < L;

    float mx[4][4];
#pragma unroll
    for (int m = 0; m < 4; ++m)
#pragma unroll
        for (int j = 0; j < 4; ++j) {
            float v = -3.0e38f;
#pragma unroll
            for (int n = 0; n < 4; ++n)
                if (valid[n]) v = fmaxf(v, acc[m][n][j]);
#pragma unroll
            for (int off = 8; off >= 1; off >>= 1) v = fmaxf(v, __shfl_xor(v, off, 64));
            mx[m][j] = v;
        }
    if (fr == 0) {
#pragma unroll
        for (int m = 0; m < 4; ++m)
#pragma unroll
            for (int j = 0; j < 4; ++j) red[0][m * 16 + quad * 4 + j][w] = mx[m][j];
    }
    __syncthreads();
    float rmax[4][4];
#pragma unroll
    for (int m = 0; m < 4; ++m)
#pragma unroll
        for (int j = 0; j < 4; ++j) {
            const int row = m * 16 + quad * 4 + j;
            float v = red[0][row][0];
#pragma unroll
            for (int ww = 1; ww < 8; ++ww) v = fmaxf(v, red[0][row][ww]);
            rmax[m][j] = v;
        }

    float sum[4][4];
#pragma unroll
    for (int m = 0; m < 4; ++m)
#pragma unroll
        for (int j = 0; j < 4; ++j) {
            float s = 0.f;
#pragma unroll
            for (int n = 0; n < 4; ++n) {
                float e = valid[n] ? __expf(acc[m][n][j] - rmax[m][j]) : 0.f;
                acc[m][n][j] = e;
                s += e;
            }
#pragma unroll
            for (int off = 8; off >= 1; off >>= 1) s += __shfl_xor(s, off, 64);
            sum[m][j] = s;
        }
    if (fr == 0) {
#pragma unroll
        for (int m = 0; m < 4; ++m)
#pragma unroll
            for (int j = 0; j < 4; ++j) red[1][m * 16 + quad * 4 + j][w] = sum[m][j];
    }
    __syncthreads();
#pragma unroll
    for (int m = 0; m < 4; ++m)
#pragma unroll
        for (int j = 0; j < 4; ++j) {
            const int row = m * 16 + quad * 4 + j;
            float s = 0.f;
#pragma unroll
            for (int ww = 0; ww < 8; ++ww) s += red[1][row][ww];
            const float inv = 1.f / s;
#pragma unroll
            for (int n = 0; n < 4; ++n)
                P[(row0 + row) * 512 + w * 64 + n * 16 + fr] =
                    __float2bfloat16(acc[m][n][j] * inv);
        }
}

extern "C" void kernel_launch(void* const* d_in, const int* in_sizes, int n_in,
                              void* d_out, int out_size, void* d_ws, size_t ws_size,
                              hipStream_t stream) {
    const float* X = (const float*)d_in[0];
    const int* sen = (const int*)d_in[1];
    const float* W = (const float*)d_in[2];
    const float* bias = (const float*)d_in[3];
    const float* U = (const float*)d_in[4];
    float* out = (float*)d_out;

    const int B = 64, T = 512, H = 1024, A = 256;
    const long M = (long)B * T;  // 32768

    // workspace: Xt (64Mi) | P (32Mi) | Wt (0.5Mi) | Ut (0.25Mi)
    char* ws = (char*)d_ws;
    __hip_bfloat16* Xt = (__hip_bfloat16*)ws;
    __hip_bfloat16* Pbf = (__hip_bfloat16*)(ws + M * H * 2);
    __hip_bfloat16* Wt = (__hip_bfloat16*)(ws + M * H * 2 + M * T * 2);
    __hip_bfloat16* Ut = (__hip_bfloat16*)((char*)Wt + (long)H * A * 2);

    // d_out scratch: alpha bf16 at [64Mi,80Mi) — dead before Z overwrites d_out
    __hip_bfloat16* alpha = (__hip_bfloat16*)((char*)d_out + M * H * 2);

    // 1. X f32 -> Xt bf16 directly (full-row writes, chunked XCD swizzle)
    transpose_x_kernel<<<dim3(16, 64), 512, 0, stream>>>(X, Xt);
    // 2. W^T [A][H], U^T [T][A]
    transpose_cvt_kernel<<<(H * A) / 256, 256, 0, stream>>>(W, Wt, H, A);
    transpose_cvt_kernel<<<(A * T) / 256, 256, 0, stream>>>(U, Ut, A, T);
    // 3. alpha = tanh(X*W + b), A-side from f32 X (L3-warm), 256 wgs
    gemm_xw_kernel<<<dim3(2, 128), 512, 0, stream>>>(X, Wt, alpha, bias);
    // 4+5. P = softmax(alpha * U^T, mask) fused, bf16
    score_softmax_kernel<<<(int)(M / 64), 512, 0, stream>>>(alpha, Ut, Pbf, sen);
    // 6. Z = P * X  (batched; Bt = Xt)  256x256 tile -> 512 wgs
    gemm_bt2_kernel<256, 256, 2, 4, 0, 0><<<dim3(H / 256, T / 256, B), 512, 0, stream>>>(
        Pbf, (long)T * T, T, Xt, (long)H * T, T, (void*)out, (long)T * H, H,
        nullptr, T);
}

// Round 8
// 159.252 us; speedup vs baseline: 1.1468x; 1.0958x over previous
//
#include <hip/hip_runtime.h>
#include <hip/hip_bf16.h>

typedef short short8 __attribute__((ext_vector_type(8)));
typedef short short4v __attribute__((ext_vector_type(4)));
typedef float f32x4 __attribute__((ext_vector_type(4)));
typedef __bf16 bf16x8 __attribute__((ext_vector_type(8)));

// ---- stage a ROWSx64 bf16 tile via global_load_lds, 16B-chunk XOR swizzle --
template <int ROWS>
__device__ __forceinline__ void stage2(const __hip_bfloat16* __restrict__ g,
                                       int ld, short* lds, int t) {
    const int w = t >> 6;
    const int lane = t & 63;
#pragma unroll
    for (int i = 0; i < ROWS / 64; ++i) {
        const int cb = i * 512 + w * 64;     // wave-uniform chunk base
        const int c = cb + lane;
        const int row = c >> 3;
        const int kc = (c & 7) ^ (row & 7);
        __builtin_amdgcn_global_load_lds((const void*)(g + (long)row * ld + kc * 8),
                                         (void*)(lds + cb * 8), 16, 0, 0);
    }
}

// ---------------- gemm_xw: alpha = tanh(X_f32 * Wt^T + b) ------------------
// BM=256(t) x BN=128(a) x BK=64(h), K=1024, 512 thr, waves 4x2, MR=NR=4.
// A-side reg-staged from f32 X (T14 split); B-side via global_load_lds.
__global__ __launch_bounds__(512, 2) void gemm_xw_kernel(
    const float* __restrict__ Xf,           // [32768][1024]
    const __hip_bfloat16* __restrict__ Wt,  // [256][1024]
    __hip_bfloat16* __restrict__ alpha,     // [32768][256]
    const float* __restrict__ bias) {
    __shared__ __align__(16) short sm[2][24576];  // A 16384 | B 8192 shorts

    int bx = blockIdx.x, by = blockIdx.y;
    {   // T1 swizzle, nwg = 256
        const int nx = gridDim.x, ny = gridDim.y;
        const int nwg = nx * ny;
        const int lin = bx + nx * by;
        const int swz = (lin & 7) * (nwg >> 3) + (lin >> 3);
        bx = swz % nx;
        by = swz / nx;
    }

    const int t = threadIdx.x;
    const int w = t >> 6, lane = t & 63;
    const int wm = w >> 1, wn = w & 1;
    const int fr = lane & 15, quad = lane >> 4;

    const float* Ab = Xf + (long)by * 256 * 1024;
    const __hip_bfloat16* Bb = Wt + (long)bx * 128 * 1024;

    int arow[4], akc[4];
#pragma unroll
    for (int i = 0; i < 4; ++i) {
        const int c = i * 512 + t;
        arow[i] = c >> 3;
        akc[i] = ((c & 7) ^ (arow[i] & 7)) * 8;
    }

    f32x4 acc[4][4] = {};
    float4 rA[4][2];

#pragma unroll
    for (int i = 0; i < 4; ++i) {
        const float* src = Ab + (long)arow[i] * 1024 + akc[i];
        rA[i][0] = *(const float4*)(src);
        rA[i][1] = *(const float4*)(src + 4);
    }
    stage2<128>(Bb, 1024, &sm[0][16384], t);
#pragma unroll
    for (int i = 0; i < 4; ++i) {
        const int c = i * 512 + t;
        __hip_bfloat16 tmp[8] __attribute__((aligned(16)));
        tmp[0] = __float2bfloat16(rA[i][0].x); tmp[1] = __float2bfloat16(rA[i][0].y);
        tmp[2] = __float2bfloat16(rA[i][0].z); tmp[3] = __float2bfloat16(rA[i][0].w);
        tmp[4] = __float2bfloat16(rA[i][1].x); tmp[5] = __float2bfloat16(rA[i][1].y);
        tmp[6] = __float2bfloat16(rA[i][1].z); tmp[7] = __float2bfloat16(rA[i][1].w);
        *(short8*)(void*)&sm[0][c * 8] = *(short8*)(void*)tmp;
    }
    __syncthreads();

    int cur = 0;
    for (int kt = 0; kt < 16; ++kt) {
        const bool more = kt + 1 < 16;
        if (more) {
#pragma unroll
            for (int i = 0; i < 4; ++i) {
                const float* src = Ab + (long)arow[i] * 1024 + (kt + 1) * 64 + akc[i];
                rA[i][0] = *(const float4*)(src);
                rA[i][1] = *(const float4*)(src + 4);
            }
            stage2<128>(Bb + (kt + 1) * 64, 1024, &sm[cur ^ 1][16384], t);
        }
        const short* At = &sm[cur][0];
        const short* Bts = &sm[cur][16384];
#pragma unroll
        for (int ks = 0; ks < 2; ++ks) {
            bf16x8 af[4], bfv[4];
            const int kc = ks * 4 + quad;
#pragma unroll
            for (int m = 0; m < 4; ++m) {
                const int row = wm * 64 + m * 16 + fr;
                const int chunk = row * 8 + (kc ^ (row & 7));
                af[m] = *(const bf16x8*)(const void*)(At + chunk * 8);
            }
#pragma unroll
            for (int n = 0; n < 4; ++n) {
                const int row = wn * 64 + n * 16 + fr;
                const int chunk = row * 8 + (kc ^ (row & 7));
                bfv[n] = *(const bf16x8*)(const void*)(Bts + chunk * 8);
            }
#pragma unroll
            for (int m = 0; m < 4; ++m)
#pragma unroll
                for (int n = 0; n < 4; ++n)
                    acc[m][n] = __builtin_amdgcn_mfma_f32_16x16x32_bf16(
                        af[m], bfv[n], acc[m][n], 0, 0, 0);
        }
        if (more) {
#pragma unroll
            for (int i = 0; i < 4; ++i) {
                const int c = i * 512 + t;
                __hip_bfloat16 tmp[8] __attribute__((aligned(16)));
                tmp[0] = __float2bfloat16(rA[i][0].x); tmp[1] = __float2bfloat16(rA[i][0].y);
                tmp[2] = __float2bfloat16(rA[i][0].z); tmp[3] = __float2bfloat16(rA[i][0].w);
                tmp[4] = __float2bfloat16(rA[i][1].x); tmp[5] = __float2bfloat16(rA[i][1].y);
                tmp[6] = __float2bfloat16(rA[i][1].z); tmp[7] = __float2bfloat16(rA[i][1].w);
                *(short8*)(void*)&sm[cur ^ 1][c * 8] = *(short8*)(void*)tmp;
            }
            __syncthreads();
        }
        cur ^= 1;
    }

    const long rowBase = (long)by * 256 + wm * 64;
    const int colBase = bx * 128 + wn * 64;
#pragma unroll
    for (int m = 0; m < 4; ++m) {
#pragma unroll
        for (int n = 0; n < 4; ++n) {
            const int col = colBase + n * 16 + fr;
            const float bv = bias[col];
#pragma unroll
            for (int j = 0; j < 4; ++j) {
                const long row = rowBase + m * 16 + quad * 4 + j;
                alpha[row * 256 + col] = __float2bfloat16(tanhf(acc[m][n][j] + bv));
            }
        }
    }
}

// -------- gemm_pv: Z = P * X, B (X f32 row-major) reg-staged TRANSPOSED ----
// Tile 256t x 256h x BK=32s, K=512. 512 thr = 8 waves (2x4), MR=8 NR=4.
// LDS/buf: A [256r x 4 granules] 16KB (gload_lds, XOR (quad^((row>>1)&3)));
//          B [256h][40s-pad] 20KB (ds_write_b32 of s-pairs, conflict-free).
// Total 72KB -> 2 blocks/CU. T14: B global loads issued before MFMA,
// cvt+ds_write after; single barrier per K-step.
__global__ __launch_bounds__(512, 2) void gemm_pv_kernel(
    const __hip_bfloat16* __restrict__ P,  // [B*512][512]
    const float* __restrict__ Xf,          // [B*512][1024]
    float* __restrict__ Z) {               // [B*512][1024]
    __shared__ __align__(16) short smA[2][8192];
    __shared__ __align__(16) short smB[2][10240];

    int bx = blockIdx.x, by = blockIdx.y, bz = blockIdx.z;
    {   // T1 bijective XCD-chunked swizzle, nwg = 4*2*64 = 512
        const int nx = gridDim.x, ny = gridDim.y;
        const int nwg = nx * ny * gridDim.z;
        const int lin = bx + nx * (by + ny * bz);
        const int swz = (lin & 7) * (nwg >> 3) + (lin >> 3);
        bx = swz % nx;
        const int r = swz / nx;
        by = r % ny;
        bz = r / ny;
    }

    const int t = threadIdx.x;
    const int w = t >> 6, lane = t & 63;
    const int wm = w >> 2, wn = w & 3;   // 2 x 4 waves
    const int fr = lane & 15, quad = lane >> 4;

    const __hip_bfloat16* Ab = P + ((long)bz * 512 + by * 256) * 512;
    const float* Bb = Xf + (long)bz * 512 * 1024 + bx * 256;

    // A staging slots (2 per thread)
    int acb[2], arow[2], akc[2];
#pragma unroll
    for (int i = 0; i < 2; ++i) {
        acb[i] = i * 512 + w * 64;           // wave-uniform
        const int s = acb[i] + lane;
        arow[i] = s >> 2;
        akc[i] = ((s & 3) ^ ((arow[i] >> 1) & 3)) * 8;
    }
    // B thread mapping: s-pair 2bi,2bi+1 ; h = bhc*8 + j
    const int bi = t & 15;
    const int bhc = t >> 4;

    f32x4 acc[8][4] = {};
    float4 r0a, r0b, r1a, r1b;

    // prologue: tile 0 into buf 0
#pragma unroll
    for (int i = 0; i < 2; ++i)
        __builtin_amdgcn_global_load_lds(
            (const void*)(Ab + (long)arow[i] * 512 + akc[i]),
            (void*)(&smA[0][acb[i] * 8]), 16, 0, 0);
    {
        const float* s0 = Bb + (long)(2 * bi) * 1024 + bhc * 8;
        const float* s1 = s0 + 1024;
        r0a = *(const float4*)(s0);     r0b = *(const float4*)(s0 + 4);
        r1a = *(const float4*)(s1);     r1b = *(const float4*)(s1 + 4);
        int* dst = (int*)(void*)&smB[0][bhc * 8 * 40 + bi * 2];
#pragma unroll
        for (int j = 0; j < 8; ++j) {
            const float v0 = j < 4 ? ((const float*)&r0a)[j] : ((const float*)&r0b)[j - 4];
            const float v1 = j < 4 ? ((const float*)&r1a)[j] : ((const float*)&r1b)[j - 4];
            __hip_bfloat16 h0 = __float2bfloat16(v0), h1 = __float2bfloat16(v1);
            dst[j * 20] = (int)*(unsigned short*)&h0 |
                          ((int)*(unsigned short*)&h1 << 16);
        }
    }
    __syncthreads();

    int cur = 0;
    for (int kt = 0; kt < 16; ++kt) {  // K = 512, BK = 32
        const bool more = kt + 1 < 16;
        if (more) {  // issue next-tile loads BEFORE compute
#pragma unroll
            for (int i = 0; i < 2; ++i)
                __builtin_amdgcn_global_load_lds(
                    (const void*)(Ab + (long)arow[i] * 512 + (kt + 1) * 32 + akc[i]),
                    (void*)(&smA[cur ^ 1][acb[i] * 8]), 16, 0, 0);
            const float* s0 = Bb + (long)((kt + 1) * 32 + 2 * bi) * 1024 + bhc * 8;
            const float* s1 = s0 + 1024;
            r0a = *(const float4*)(s0);     r0b = *(const float4*)(s0 + 4);
            r1a = *(const float4*)(s1);     r1b = *(const float4*)(s1 + 4);
        }
        // compute from buf[cur]
        {
            const short* At = &smA[cur][0];
            const short* Bt = &smB[cur][0];
            bf16x8 bfv[4];
#pragma unroll
            for (int n = 0; n < 4; ++n) {
                const int h = wn * 64 + n * 16 + fr;
                bfv[n] = *(const bf16x8*)(const void*)(Bt + h * 40 + quad * 8);
            }
#pragma unroll
            for (int m = 0; m < 8; ++m) {
                const int row = wm * 128 + m * 16 + fr;
                const int slot = row * 4 + (quad ^ ((row >> 1) & 3));
                const bf16x8 af = *(const bf16x8*)(const void*)(At + slot * 8);
#pragma unroll
                for (int n = 0; n < 4; ++n)
                    acc[m][n] = __builtin_amdgcn_mfma_f32_16x16x32_bf16(
                        af, bfv[n], acc[m][n], 0, 0, 0);
            }
        }
        if (more) {  // cvt + LDS-write prefetched B, then barrier
            int* dst = (int*)(void*)&smB[cur ^ 1][bhc * 8 * 40 + bi * 2];
#pragma unroll
            for (int j = 0; j < 8; ++j) {
                const float v0 = j < 4 ? ((const float*)&r0a)[j] : ((const float*)&r0b)[j - 4];
                const float v1 = j < 4 ? ((const float*)&r1a)[j] : ((const float*)&r1b)[j - 4];
                __hip_bfloat16 h0 = __float2bfloat16(v0), h1 = __float2bfloat16(v1);
                dst[j * 20] = (int)*(unsigned short*)&h0 |
                              ((int)*(unsigned short*)&h1 << 16);
            }
            __syncthreads();
        }
        cur ^= 1;
    }

    // epilogue: C/D layout col = lane&15, row = (lane>>4)*4 + j
    const long rowBase = (long)bz * 512 + by * 256 + wm * 128;
    const int colBase = bx * 256 + wn * 64;
#pragma unroll
    for (int m = 0; m < 8; ++m) {
#pragma unroll
        for (int n = 0; n < 4; ++n) {
            const int col = colBase + n * 16 + fr;
#pragma unroll
            for (int j = 0; j < 4; ++j) {
                const long row = rowBase + m * 16 + quad * 4 + j;
                Z[row * 1024 + col] = acc[m][n][j];
            }
        }
    }
}

// naive small transpose+convert: in [R][C] f32 -> out [C][R] bf16
__global__ __launch_bounds__(256) void transpose_cvt_kernel(const float* __restrict__ in,
                                                            __hip_bfloat16* __restrict__ out,
                                                            int R, int C) {
    const int o = blockIdx.x * 256 + threadIdx.x;
    if (o >= R * C) return;
    const int c = o / R;
    const int r = o - c * R;
    out[o] = __float2bfloat16(in[(long)r * C + c]);
}

// Fused scores+masked-softmax: per block, 64 query rows x full 512 key cols.
__global__ __launch_bounds__(512) void score_softmax_kernel(
    const __hip_bfloat16* __restrict__ Aa,  // alpha [32768][256]
    const __hip_bfloat16* __restrict__ Ut,  // [512][256]
    __hip_bfloat16* __restrict__ P,         // [32768][512]
    const int* __restrict__ sen) {
    __shared__ __align__(16) short At[64 * 64];
    __shared__ __align__(16) short Bts[512 * 64];
    __shared__ float red[2][64][9];

    const int t = threadIdx.x;
    const int w = t >> 6, lane = t & 63;
    const int fr = lane & 15, quad = lane >> 4;
    const long row0 = (long)blockIdx.x * 64;
    const __hip_bfloat16* Ab = Aa + row0 * 256;

    f32x4 acc[4][4] = {};

    for (int kt = 0; kt < 4; ++kt) {  // K = 256, BK = 64
        if (kt) __syncthreads();
        {
            const int cb = w * 64;
            const int c = cb + lane;
            const int row = c >> 3, kc = (c & 7) ^ (row & 7);
            __builtin_amdgcn_global_load_lds(
                (const void*)(Ab + (long)row * 256 + kt * 64 + kc * 8),
                (void*)(At + cb * 8), 16, 0, 0);
        }
#pragma unroll
        for (int i = 0; i < 8; ++i) {
            const int cb = i * 512 + w * 64;
            const int c = cb + lane;
            const int row = c >> 3, kc = (c & 7) ^ (row & 7);
            __builtin_amdgcn_global_load_lds(
                (const void*)(Ut + (long)row * 256 + kt * 64 + kc * 8),
                (void*)(Bts + cb * 8), 16, 0, 0);
        }
        __syncthreads();
#pragma unroll
        for (int ks = 0; ks < 2; ++ks) {
            bf16x8 af[4], bfv[4];
            const int kc = ks * 4 + quad;
#pragma unroll
            for (int m = 0; m < 4; ++m) {
                const int row = m * 16 + fr;
                const int chunk = row * 8 + (kc ^ (row & 7));
                af[m] = *(const bf16x8*)(const void*)(At + chunk * 8);
            }
#pragma unroll
            for (int n = 0; n < 4; ++n) {
                const int row = w * 64 + n * 16 + fr;
                const int chunk = row * 8 + (kc ^ (row & 7));
                bfv[n] = *(const bf16x8*)(const void*)(Bts + chunk * 8);
            }
#pragma unroll
            for (int m = 0; m < 4; ++m)
#pragma unroll
                for (int n = 0; n < 4; ++n)
                    acc[m][n] = __builtin_amdgcn_mfma_f32_16x16x32_bf16(
                        af[m], bfv[n], acc[m][n], 0, 0, 0);
        }
    }
    __syncthreads();

    const int L = sen[row0 >> 9];
    bool valid[4];
#pragma unroll
    for (int n = 0; n < 4; ++n) valid[n] = (w * 64 + n * 16 + fr) < L;

    float mx[4][4];
#pragma unroll
    for (int m = 0; m < 4; ++m)
#pragma unroll
        for (int j = 0; j < 4; ++j) {
            float v = -3.0e38f;
#pragma unroll
            for (int n = 0; n < 4; ++n)
                if (valid[n]) v = fmaxf(v, acc[m][n][j]);
#pragma unroll
            for (int off = 8; off >= 1; off >>= 1) v = fmaxf(v, __shfl_xor(v, off, 64));
            mx[m][j] = v;
        }
    if (fr == 0) {
#pragma unroll
        for (int m = 0; m < 4; ++m)
#pragma unroll
            for (int j = 0; j < 4; ++j) red[0][m * 16 + quad * 4 + j][w] = mx[m][j];
    }
    __syncthreads();
    float rmax[4][4];
#pragma unroll
    for (int m = 0; m < 4; ++m)
#pragma unroll
        for (int j = 0; j < 4; ++j) {
            const int row = m * 16 + quad * 4 + j;
            float v = red[0][row][0];
#pragma unroll
            for (int ww = 1; ww < 8; ++ww) v = fmaxf(v, red[0][row][ww]);
            rmax[m][j] = v;
        }

    float sum[4][4];
#pragma unroll
    for (int m = 0; m < 4; ++m)
#pragma unroll
        for (int j = 0; j < 4; ++j) {
            float s = 0.f;
#pragma unroll
            for (int n = 0; n < 4; ++n) {
                float e = valid[n] ? __expf(acc[m][n][j] - rmax[m][j]) : 0.f;
                acc[m][n][j] = e;
                s += e;
            }
#pragma unroll
            for (int off = 8; off >= 1; off >>= 1) s += __shfl_xor(s, off, 64);
            sum[m][j] = s;
        }
    if (fr == 0) {
#pragma unroll
        for (int m = 0; m < 4; ++m)
#pragma unroll
            for (int j = 0; j < 4; ++j) red[1][m * 16 + quad * 4 + j][w] = sum[m][j];
    }
    __syncthreads();
#pragma unroll
    for (int m = 0; m < 4; ++m)
#pragma unroll
        for (int j = 0; j < 4; ++j) {
            const int row = m * 16 + quad * 4 + j;
            float s = 0.f;
#pragma unroll
            for (int ww = 0; ww < 8; ++ww) s += red[1][row][ww];
            const float inv = 1.f / s;
#pragma unroll
            for (int n = 0; n < 4; ++n)
                P[(row0 + row) * 512 + w * 64 + n * 16 + fr] =
                    __float2bfloat16(acc[m][n][j] * inv);
        }
}

extern "C" void kernel_launch(void* const* d_in, const int* in_sizes, int n_in,
                              void* d_out, int out_size, void* d_ws, size_t ws_size,
                              hipStream_t stream) {
    const float* X = (const float*)d_in[0];
    const int* sen = (const int*)d_in[1];
    const float* W = (const float*)d_in[2];
    const float* bias = (const float*)d_in[3];
    const float* U = (const float*)d_in[4];
    float* out = (float*)d_out;

    const int B = 64, T = 512, H = 1024, A = 256;
    const long M = (long)B * T;  // 32768

    // workspace: P (32Mi) | Wt (0.5Mi) | Ut (0.25Mi)  — no Xt/Xbf anymore
    char* ws = (char*)d_ws;
    __hip_bfloat16* Pbf = (__hip_bfloat16*)ws;
    __hip_bfloat16* Wt = (__hip_bfloat16*)(ws + M * T * 2);
    __hip_bfloat16* Ut = (__hip_bfloat16*)((char*)Wt + (long)H * A * 2);

    // d_out scratch: alpha bf16 at [64Mi,80Mi) — consumed by score_softmax
    // before gemm_pv overwrites all of d_out with Z.
    __hip_bfloat16* alpha = (__hip_bfloat16*)((char*)d_out + M * H * 2);

    // 1. W^T [A][H], U^T [T][A]
    transpose_cvt_kernel<<<(H * A) / 256, 256, 0, stream>>>(W, Wt, H, A);
    transpose_cvt_kernel<<<(A * T) / 256, 256, 0, stream>>>(U, Ut, A, T);
    // 2. alpha = tanh(X*W + b), A-side reg-staged from f32 X, 256 wgs
    gemm_xw_kernel<<<dim3(2, 128), 512, 0, stream>>>(X, Wt, alpha, bias);
    // 3. P = softmax(alpha * U^T, mask) fused, bf16
    score_softmax_kernel<<<(int)(M / 64), 512, 0, stream>>>(alpha, Ut, Pbf, sen);
    // 4. Z = P * X  — B-side reg-staged transposed from f32 X; no Xt needed
    gemm_pv_kernel<<<dim3(H / 256, T / 256, B), 512, 0, stream>>>(Pbf, X, out);
}

// Round 9
// 157.840 us; speedup vs baseline: 1.1571x; 1.0089x over previous
//
#include <hip/hip_runtime.h>
#include <hip/hip_bf16.h>

typedef short short8 __attribute__((ext_vector_type(8)));
typedef short short4v __attribute__((ext_vector_type(4)));
typedef float f32x4 __attribute__((ext_vector_type(4)));
typedef __bf16 bf16x8 __attribute__((ext_vector_type(8)));

// ---- stage a ROWSx64 bf16 tile via global_load_lds, 16B-chunk XOR swizzle --
template <int ROWS>
__device__ __forceinline__ void stage2(const __hip_bfloat16* __restrict__ g,
                                       int ld, short* lds, int t) {
    const int w = t >> 6;
    const int lane = t & 63;
#pragma unroll
    for (int i = 0; i < ROWS / 64; ++i) {
        const int cb = i * 512 + w * 64;     // wave-uniform chunk base
        const int c = cb + lane;
        const int row = c >> 3;
        const int kc = (c & 7) ^ (row & 7);
        __builtin_amdgcn_global_load_lds((const void*)(g + (long)row * ld + kc * 8),
                                         (void*)(lds + cb * 8), 16, 0, 0);
    }
}

// ---------------- gemm_xw: alpha = tanh(X_f32 * Wt^T + b) ------------------
// BM=256(t) x BN=128(a) x BK=64(h), K=1024, 512 thr, waves 4x2, MR=NR=4.
// A-side reg-staged from f32 X (T14 split); B-side via global_load_lds.
__global__ __launch_bounds__(512, 2) void gemm_xw_kernel(
    const float* __restrict__ Xf,           // [32768][1024]
    const __hip_bfloat16* __restrict__ Wt,  // [256][1024]
    __hip_bfloat16* __restrict__ alpha,     // [32768][256]
    const float* __restrict__ bias) {
    __shared__ __align__(16) short sm[2][24576];  // A 16384 | B 8192 shorts

    int bx = blockIdx.x, by = blockIdx.y;
    {   // T1 swizzle, nwg = 256
        const int nx = gridDim.x, ny = gridDim.y;
        const int nwg = nx * ny;
        const int lin = bx + nx * by;
        const int swz = (lin & 7) * (nwg >> 3) + (lin >> 3);
        bx = swz % nx;
        by = swz / nx;
    }

    const int t = threadIdx.x;
    const int w = t >> 6, lane = t & 63;
    const int wm = w >> 1, wn = w & 1;
    const int fr = lane & 15, quad = lane >> 4;

    const float* Ab = Xf + (long)by * 256 * 1024;
    const __hip_bfloat16* Bb = Wt + (long)bx * 128 * 1024;

    int arow[4], akc[4];
#pragma unroll
    for (int i = 0; i < 4; ++i) {
        const int c = i * 512 + t;
        arow[i] = c >> 3;
        akc[i] = ((c & 7) ^ (arow[i] & 7)) * 8;
    }

    f32x4 acc[4][4] = {};
    float4 rA[4][2];

#pragma unroll
    for (int i = 0; i < 4; ++i) {
        const float* src = Ab + (long)arow[i] * 1024 + akc[i];
        rA[i][0] = *(const float4*)(src);
        rA[i][1] = *(const float4*)(src + 4);
    }
    stage2<128>(Bb, 1024, &sm[0][16384], t);
#pragma unroll
    for (int i = 0; i < 4; ++i) {
        const int c = i * 512 + t;
        __hip_bfloat16 tmp[8] __attribute__((aligned(16)));
        tmp[0] = __float2bfloat16(rA[i][0].x); tmp[1] = __float2bfloat16(rA[i][0].y);
        tmp[2] = __float2bfloat16(rA[i][0].z); tmp[3] = __float2bfloat16(rA[i][0].w);
        tmp[4] = __float2bfloat16(rA[i][1].x); tmp[5] = __float2bfloat16(rA[i][1].y);
        tmp[6] = __float2bfloat16(rA[i][1].z); tmp[7] = __float2bfloat16(rA[i][1].w);
        *(short8*)(void*)&sm[0][c * 8] = *(short8*)(void*)tmp;
    }
    __syncthreads();

    int cur = 0;
    for (int kt = 0; kt < 16; ++kt) {
        const bool more = kt + 1 < 16;
        if (more) {
#pragma unroll
            for (int i = 0; i < 4; ++i) {
                const float* src = Ab + (long)arow[i] * 1024 + (kt + 1) * 64 + akc[i];
                rA[i][0] = *(const float4*)(src);
                rA[i][1] = *(const float4*)(src + 4);
            }
            stage2<128>(Bb + (kt + 1) * 64, 1024, &sm[cur ^ 1][16384], t);
        }
        const short* At = &sm[cur][0];
        const short* Bts = &sm[cur][16384];
#pragma unroll
        for (int ks = 0; ks < 2; ++ks) {
            bf16x8 af[4], bfv[4];
            const int kc = ks * 4 + quad;
#pragma unroll
            for (int m = 0; m < 4; ++m) {
                const int row = wm * 64 + m * 16 + fr;
                const int chunk = row * 8 + (kc ^ (row & 7));
                af[m] = *(const bf16x8*)(const void*)(At + chunk * 8);
            }
#pragma unroll
            for (int n = 0; n < 4; ++n) {
                const int row = wn * 64 + n * 16 + fr;
                const int chunk = row * 8 + (kc ^ (row & 7));
                bfv[n] = *(const bf16x8*)(const void*)(Bts + chunk * 8);
            }
#pragma unroll
            for (int m = 0; m < 4; ++m)
#pragma unroll
                for (int n = 0; n < 4; ++n)
                    acc[m][n] = __builtin_amdgcn_mfma_f32_16x16x32_bf16(
                        af[m], bfv[n], acc[m][n], 0, 0, 0);
        }
        if (more) {
#pragma unroll
            for (int i = 0; i < 4; ++i) {
                const int c = i * 512 + t;
                __hip_bfloat16 tmp[8] __attribute__((aligned(16)));
                tmp[0] = __float2bfloat16(rA[i][0].x); tmp[1] = __float2bfloat16(rA[i][0].y);
                tmp[2] = __float2bfloat16(rA[i][0].z); tmp[3] = __float2bfloat16(rA[i][0].w);
                tmp[4] = __float2bfloat16(rA[i][1].x); tmp[5] = __float2bfloat16(rA[i][1].y);
                tmp[6] = __float2bfloat16(rA[i][1].z); tmp[7] = __float2bfloat16(rA[i][1].w);
                *(short8*)(void*)&sm[cur ^ 1][c * 8] = *(short8*)(void*)tmp;
            }
            __syncthreads();
        }
        cur ^= 1;
    }

    const long rowBase = (long)by * 256 + wm * 64;
    const int colBase = bx * 128 + wn * 64;
#pragma unroll
    for (int m = 0; m < 4; ++m) {
#pragma unroll
        for (int n = 0; n < 4; ++n) {
            const int col = colBase + n * 16 + fr;
            const float bv = bias[col];
#pragma unroll
            for (int j = 0; j < 4; ++j) {
                const long row = rowBase + m * 16 + quad * 4 + j;
                alpha[row * 256 + col] = __float2bfloat16(tanhf(acc[m][n][j] + bv));
            }
        }
    }
}

// -------- gemm_pv v2: Z = P * X, retiled for 2 blocks/CU occupancy ---------
// Tile 256t x 128h x BK=32s, K=512. 512 thr = 8 waves (4wm x 2wn), wave tile
// 64x64 -> acc 4x4 f32x4 = 64 regs (was 128: the r8 occupancy killer).
// LDS: A [256r][32s] 16KB (gload_lds, XOR (quad^((row>>1)&3)));
//      B [128h][40s-pad] 10KB (ds_write_b32 s-pairs, lanes->consecutive
//      dwords, conflict-free). 52KB dbuf total -> 2 blocks/CU at 128 regs.
__global__ __launch_bounds__(512, 4) void gemm_pv_kernel(
    const __hip_bfloat16* __restrict__ P,  // [B*512][512]
    const float* __restrict__ Xf,          // [B*512][1024]
    float* __restrict__ Z) {               // [B*512][1024]
    __shared__ __align__(16) short smA[2][8192];   // 16KB each
    __shared__ __align__(16) short smB[2][5120];   // 10KB each

    int bx = blockIdx.x, by = blockIdx.y, bz = blockIdx.z;
    {   // T1 bijective XCD-chunked swizzle, nwg = 8*2*64 = 1024
        const int nx = gridDim.x, ny = gridDim.y;
        const int nwg = nx * ny * gridDim.z;
        const int lin = bx + nx * (by + ny * bz);
        const int swz = (lin & 7) * (nwg >> 3) + (lin >> 3);
        bx = swz % nx;
        const int r = swz / nx;
        by = r % ny;
        bz = r / ny;
    }

    const int t = threadIdx.x;
    const int w = t >> 6, lane = t & 63;
    const int wm = w >> 1, wn = w & 1;   // 4 x 2 waves
    const int fr = lane & 15, quad = lane >> 4;

    const __hip_bfloat16* Ab = P + ((long)bz * 512 + by * 256) * 512;
    const float* Bb = Xf + (long)bz * 512 * 1024 + bx * 128;

    // A staging slots (2 granules per thread)
    int acb[2], arow[2], akc[2];
#pragma unroll
    for (int i = 0; i < 2; ++i) {
        acb[i] = i * 512 + w * 64;           // wave-uniform
        const int s = acb[i] + lane;
        arow[i] = s >> 2;
        akc[i] = ((s & 3) ^ ((arow[i] >> 1) & 3)) * 8;
    }
    // B thread mapping: s-pair (2bi, 2bi+1), h = bhc*4 + j (j=0..3)
    const int bi = t & 15;
    const int bhc = t >> 4;   // 0..31

    f32x4 acc[4][4] = {};
    float4 r0, r1;

    // prologue: tile 0 into buf 0
#pragma unroll
    for (int i = 0; i < 2; ++i)
        __builtin_amdgcn_global_load_lds(
            (const void*)(Ab + (long)arow[i] * 512 + akc[i]),
            (void*)(&smA[0][acb[i] * 8]), 16, 0, 0);
    {
        const float* s0 = Bb + (long)(2 * bi) * 1024 + bhc * 4;
        r0 = *(const float4*)(s0);
        r1 = *(const float4*)(s0 + 1024);
        int* dst = (int*)(void*)&smB[0][(bhc * 4) * 40 + bi * 2];
#pragma unroll
        for (int j = 0; j < 4; ++j) {
            __hip_bfloat16 h0 = __float2bfloat16(((const float*)&r0)[j]);
            __hip_bfloat16 h1 = __float2bfloat16(((const float*)&r1)[j]);
            dst[j * 20] = (int)*(unsigned short*)&h0 |
                          ((int)*(unsigned short*)&h1 << 16);
        }
    }
    __syncthreads();

    int cur = 0;
    for (int kt = 0; kt < 16; ++kt) {  // K = 512, BK = 32
        const bool more = kt + 1 < 16;
        if (more) {  // issue next-tile loads BEFORE compute
#pragma unroll
            for (int i = 0; i < 2; ++i)
                __builtin_amdgcn_global_load_lds(
                    (const void*)(Ab + (long)arow[i] * 512 + (kt + 1) * 32 + akc[i]),
                    (void*)(&smA[cur ^ 1][acb[i] * 8]), 16, 0, 0);
            const float* s0 = Bb + (long)((kt + 1) * 32 + 2 * bi) * 1024 + bhc * 4;
            r0 = *(const float4*)(s0);
            r1 = *(const float4*)(s0 + 1024);
        }
        // compute from buf[cur]
        {
            const short* At = &smA[cur][0];
            const short* Bt = &smB[cur][0];
            bf16x8 bfv[4];
#pragma unroll
            for (int n = 0; n < 4; ++n) {
                const int h = wn * 64 + n * 16 + fr;
                bfv[n] = *(const bf16x8*)(const void*)(Bt + h * 40 + quad * 8);
            }
#pragma unroll
            for (int m = 0; m < 4; ++m) {
                const int row = wm * 64 + m * 16 + fr;
                const int slot = row * 4 + (quad ^ ((row >> 1) & 3));
                const bf16x8 af = *(const bf16x8*)(const void*)(At + slot * 8);
#pragma unroll
                for (int n = 0; n < 4; ++n)
                    acc[m][n] = __builtin_amdgcn_mfma_f32_16x16x32_bf16(
                        af, bfv[n], acc[m][n], 0, 0, 0);
            }
        }
        if (more) {  // cvt + LDS-write prefetched B, then barrier
            int* dst = (int*)(void*)&smB[cur ^ 1][(bhc * 4) * 40 + bi * 2];
#pragma unroll
            for (int j = 0; j < 4; ++j) {
                __hip_bfloat16 h0 = __float2bfloat16(((const float*)&r0)[j]);
                __hip_bfloat16 h1 = __float2bfloat16(((const float*)&r1)[j]);
                dst[j * 20] = (int)*(unsigned short*)&h0 |
                              ((int)*(unsigned short*)&h1 << 16);
            }
            __syncthreads();
        }
        cur ^= 1;
    }

    // epilogue: C/D layout col = lane&15, row = (lane>>4)*4 + j
    const long rowBase = (long)bz * 512 + by * 256 + wm * 64;
    const int colBase = bx * 128 + wn * 64;
#pragma unroll
    for (int m = 0; m < 4; ++m) {
#pragma unroll
        for (int n = 0; n < 4; ++n) {
            const int col = colBase + n * 16 + fr;
#pragma unroll
            for (int j = 0; j < 4; ++j) {
                const long row = rowBase + m * 16 + quad * 4 + j;
                Z[row * 1024 + col] = acc[m][n][j];
            }
        }
    }
}

// naive small transpose+convert: in [R][C] f32 -> out [C][R] bf16
__global__ __launch_bounds__(256) void transpose_cvt_kernel(const float* __restrict__ in,
                                                            __hip_bfloat16* __restrict__ out,
                                                            int R, int C) {
    const int o = blockIdx.x * 256 + threadIdx.x;
    if (o >= R * C) return;
    const int c = o / R;
    const int r = o - c * R;
    out[o] = __float2bfloat16(in[(long)r * C + c]);
}

// Fused scores+masked-softmax: per block, 64 query rows x full 512 key cols.
__global__ __launch_bounds__(512) void score_softmax_kernel(
    const __hip_bfloat16* __restrict__ Aa,  // alpha [32768][256]
    const __hip_bfloat16* __restrict__ Ut,  // [512][256]
    __hip_bfloat16* __restrict__ P,         // [32768][512]
    const int* __restrict__ sen) {
    __shared__ __align__(16) short At[64 * 64];
    __shared__ __align__(16) short Bts[512 * 64];
    __shared__ float red[2][64][9];

    const int t = threadIdx.x;
    const int w = t >> 6, lane = t & 63;
    const int fr = lane & 15, quad = lane >> 4;
    const long row0 = (long)blockIdx.x * 64;
    const __hip_bfloat16* Ab = Aa + row0 * 256;

    f32x4 acc[4][4] = {};

    for (int kt = 0; kt < 4; ++kt) {  // K = 256, BK = 64
        if (kt) __syncthreads();
        {
            const int cb = w * 64;
            const int c = cb + lane;
            const int row = c >> 3, kc = (c & 7) ^ (row & 7);
            __builtin_amdgcn_global_load_lds(
                (const void*)(Ab + (long)row * 256 + kt * 64 + kc * 8),
                (void*)(At + cb * 8), 16, 0, 0);
        }
#pragma unroll
        for (int i = 0; i < 8; ++i) {
            const int cb = i * 512 + w * 64;
            const int c = cb + lane;
            const int row = c >> 3, kc = (c & 7) ^ (row & 7);
            __builtin_amdgcn_global_load_lds(
                (const void*)(Ut + (long)row * 256 + kt * 64 + kc * 8),
                (void*)(Bts + cb * 8), 16, 0, 0);
        }
        __syncthreads();
#pragma unroll
        for (int ks = 0; ks < 2; ++ks) {
            bf16x8 af[4], bfv[4];
            const int kc = ks * 4 + quad;
#pragma unroll
            for (int m = 0; m < 4; ++m) {
                const int row = m * 16 + fr;
                const int chunk = row * 8 + (kc ^ (row & 7));
                af[m] = *(const bf16x8*)(const void*)(At + chunk * 8);
            }
#pragma unroll
            for (int n = 0; n < 4; ++n) {
                const int row = w * 64 + n * 16 + fr;
                const int chunk = row * 8 + (kc ^ (row & 7));
                bfv[n] = *(const bf16x8*)(const void*)(Bts + chunk * 8);
            }
#pragma unroll
            for (int m = 0; m < 4; ++m)
#pragma unroll
                for (int n = 0; n < 4; ++n)
                    acc[m][n] = __builtin_amdgcn_mfma_f32_16x16x32_bf16(
                        af[m], bfv[n], acc[m][n], 0, 0, 0);
        }
    }
    __syncthreads();

    const int L = sen[row0 >> 9];
    bool valid[4];
#pragma unroll
    for (int n = 0; n < 4; ++n) valid[n] = (w * 64 + n * 16 + fr) < L;

    float mx[4][4];
#pragma unroll
    for (int m = 0; m < 4; ++m)
#pragma unroll
        for (int j = 0; j < 4; ++j) {
            float v = -3.0e38f;
#pragma unroll
            for (int n = 0; n < 4; ++n)
                if (valid[n]) v = fmaxf(v, acc[m][n][j]);
#pragma unroll
            for (int off = 8; off >= 1; off >>= 1) v = fmaxf(v, __shfl_xor(v, off, 64));
            mx[m][j] = v;
        }
    if (fr == 0) {
#pragma unroll
        for (int m = 0; m < 4; ++m)
#pragma unroll
            for (int j = 0; j < 4; ++j) red[0][m * 16 + quad * 4 + j][w] = mx[m][j];
    }
    __syncthreads();
    float rmax[4][4];
#pragma unroll
    for (int m = 0; m < 4; ++m)
#pragma unroll
        for (int j = 0; j < 4; ++j) {
            const int row = m * 16 + quad * 4 + j;
            float v = red[0][row][0];
#pragma unroll
            for (int ww = 1; ww < 8; ++ww) v = fmaxf(v, red[0][row][ww]);
            rmax[m][j] = v;
        }

    float sum[4][4];
#pragma unroll
    for (int m = 0; m < 4; ++m)
#pragma unroll
        for (int j = 0; j < 4; ++j) {
            float s = 0.f;
#pragma unroll
            for (int n = 0; n < 4; ++n) {
                float e = valid[n] ? __expf(acc[m][n][j] - rmax[m][j]) : 0.f;
                acc[m][n][j] = e;
                s += e;
            }
#pragma unroll
            for (int off = 8; off >= 1; off >>= 1) s += __shfl_xor(s, off, 64);
            sum[m][j] = s;
        }
    if (fr == 0) {
#pragma unroll
        for (int m = 0; m < 4; ++m)
#pragma unroll
            for (int j = 0; j < 4; ++j) red[1][m * 16 + quad * 4 + j][w] = sum[m][j];
    }
    __syncthreads();
#pragma unroll
    for (int m = 0; m < 4; ++m)
#pragma unroll
        for (int j = 0; j < 4; ++j) {
            const int row = m * 16 + quad * 4 + j;
            float s = 0.f;
#pragma unroll
            for (int ww = 0; ww < 8; ++ww) s += red[1][row][ww];
            const float inv = 1.f / s;
#pragma unroll
            for (int n = 0; n < 4; ++n)
                P[(row0 + row) * 512 + w * 64 + n * 16 + fr] =
                    __float2bfloat16(acc[m][n][j] * inv);
        }
}

extern "C" void kernel_launch(void* const* d_in, const int* in_sizes, int n_in,
                              void* d_out, int out_size, void* d_ws, size_t ws_size,
                              hipStream_t stream) {
    const float* X = (const float*)d_in[0];
    const int* sen = (const int*)d_in[1];
    const float* W = (const float*)d_in[2];
    const float* bias = (const float*)d_in[3];
    const float* U = (const float*)d_in[4];
    float* out = (float*)d_out;

    const int B = 64, T = 512, H = 1024, A = 256;
    const long M = (long)B * T;  // 32768

    // workspace: P (32Mi) | Wt (0.5Mi) | Ut (0.25Mi)
    char* ws = (char*)d_ws;
    __hip_bfloat16* Pbf = (__hip_bfloat16*)ws;
    __hip_bfloat16* Wt = (__hip_bfloat16*)(ws + M * T * 2);
    __hip_bfloat16* Ut = (__hip_bfloat16*)((char*)Wt + (long)H * A * 2);

    // d_out scratch: alpha bf16 at [64Mi,80Mi) — consumed by score_softmax
    // before gemm_pv overwrites all of d_out with Z.
    __hip_bfloat16* alpha = (__hip_bfloat16*)((char*)d_out + M * H * 2);

    // 1. W^T [A][H], U^T [T][A]
    transpose_cvt_kernel<<<(H * A) / 256, 256, 0, stream>>>(W, Wt, H, A);
    transpose_cvt_kernel<<<(A * T) / 256, 256, 0, stream>>>(U, Ut, A, T);
    // 2. alpha = tanh(X*W + b), A-side reg-staged from f32 X, 256 wgs
    gemm_xw_kernel<<<dim3(2, 128), 512, 0, stream>>>(X, Wt, alpha, bias);
    // 3. P = softmax(alpha * U^T, mask) fused, bf16
    score_softmax_kernel<<<(int)(M / 64), 512, 0, stream>>>(alpha, Ut, Pbf, sen);
    // 4. Z = P * X — retiled 256x128, 2 blocks/CU
    gemm_pv_kernel<<<dim3(H / 128, T / 256, B), 512, 0, stream>>>(Pbf, X, out);
}

// Round 10
// 144.091 us; speedup vs baseline: 1.2675x; 1.0954x over previous
//
#include <hip/hip_runtime.h>
#include <hip/hip_bf16.h>

typedef short short8 __attribute__((ext_vector_type(8)));
typedef short short4v __attribute__((ext_vector_type(4)));
typedef float f32x4 __attribute__((ext_vector_type(4)));
typedef __bf16 bf16x8 __attribute__((ext_vector_type(8)));

// ---- stage a ROWSx64 bf16 tile via global_load_lds, 16B-chunk XOR swizzle --
template <int ROWS>
__device__ __forceinline__ void stage2(const __hip_bfloat16* __restrict__ g,
                                       int ld, short* lds, int t) {
    const int w = t >> 6;
    const int lane = t & 63;
#pragma unroll
    for (int i = 0; i < ROWS / 64; ++i) {
        const int cb = i * 512 + w * 64;     // wave-uniform chunk base
        const int c = cb + lane;
        const int row = c >> 3;
        const int kc = (c & 7) ^ (row & 7);
        __builtin_amdgcn_global_load_lds((const void*)(g + (long)row * ld + kc * 8),
                                         (void*)(lds + cb * 8), 16, 0, 0);
    }
}

// ---------------- gemm_xw: alpha = tanh(X_f32 * Wt^T + b) ------------------
// (unchanged from r9 — frozen while gemm_pv's pipeline change is validated)
__global__ __launch_bounds__(512, 2) void gemm_xw_kernel(
    const float* __restrict__ Xf,           // [32768][1024]
    const __hip_bfloat16* __restrict__ Wt,  // [256][1024]
    __hip_bfloat16* __restrict__ alpha,     // [32768][256]
    const float* __restrict__ bias) {
    __shared__ __align__(16) short sm[2][24576];  // A 16384 | B 8192 shorts

    int bx = blockIdx.x, by = blockIdx.y;
    {   // T1 swizzle, nwg = 256
        const int nx = gridDim.x, ny = gridDim.y;
        const int nwg = nx * ny;
        const int lin = bx + nx * by;
        const int swz = (lin & 7) * (nwg >> 3) + (lin >> 3);
        bx = swz % nx;
        by = swz / nx;
    }

    const int t = threadIdx.x;
    const int w = t >> 6, lane = t & 63;
    const int wm = w >> 1, wn = w & 1;
    const int fr = lane & 15, quad = lane >> 4;

    const float* Ab = Xf + (long)by * 256 * 1024;
    const __hip_bfloat16* Bb = Wt + (long)bx * 128 * 1024;

    int arow[4], akc[4];
#pragma unroll
    for (int i = 0; i < 4; ++i) {
        const int c = i * 512 + t;
        arow[i] = c >> 3;
        akc[i] = ((c & 7) ^ (arow[i] & 7)) * 8;
    }

    f32x4 acc[4][4] = {};
    float4 rA[4][2];

#pragma unroll
    for (int i = 0; i < 4; ++i) {
        const float* src = Ab + (long)arow[i] * 1024 + akc[i];
        rA[i][0] = *(const float4*)(src);
        rA[i][1] = *(const float4*)(src + 4);
    }
    stage2<128>(Bb, 1024, &sm[0][16384], t);
#pragma unroll
    for (int i = 0; i < 4; ++i) {
        const int c = i * 512 + t;
        __hip_bfloat16 tmp[8] __attribute__((aligned(16)));
        tmp[0] = __float2bfloat16(rA[i][0].x); tmp[1] = __float2bfloat16(rA[i][0].y);
        tmp[2] = __float2bfloat16(rA[i][0].z); tmp[3] = __float2bfloat16(rA[i][0].w);
        tmp[4] = __float2bfloat16(rA[i][1].x); tmp[5] = __float2bfloat16(rA[i][1].y);
        tmp[6] = __float2bfloat16(rA[i][1].z); tmp[7] = __float2bfloat16(rA[i][1].w);
        *(short8*)(void*)&sm[0][c * 8] = *(short8*)(void*)tmp;
    }
    __syncthreads();

    int cur = 0;
    for (int kt = 0; kt < 16; ++kt) {
        const bool more = kt + 1 < 16;
        if (more) {
#pragma unroll
            for (int i = 0; i < 4; ++i) {
                const float* src = Ab + (long)arow[i] * 1024 + (kt + 1) * 64 + akc[i];
                rA[i][0] = *(const float4*)(src);
                rA[i][1] = *(const float4*)(src + 4);
            }
            stage2<128>(Bb + (kt + 1) * 64, 1024, &sm[cur ^ 1][16384], t);
        }
        const short* At = &sm[cur][0];
        const short* Bts = &sm[cur][16384];
#pragma unroll
        for (int ks = 0; ks < 2; ++ks) {
            bf16x8 af[4], bfv[4];
            const int kc = ks * 4 + quad;
#pragma unroll
            for (int m = 0; m < 4; ++m) {
                const int row = wm * 64 + m * 16 + fr;
                const int chunk = row * 8 + (kc ^ (row & 7));
                af[m] = *(const bf16x8*)(const void*)(At + chunk * 8);
            }
#pragma unroll
            for (int n = 0; n < 4; ++n) {
                const int row = wn * 64 + n * 16 + fr;
                const int chunk = row * 8 + (kc ^ (row & 7));
                bfv[n] = *(const bf16x8*)(const void*)(Bts + chunk * 8);
            }
#pragma unroll
            for (int m = 0; m < 4; ++m)
#pragma unroll
                for (int n = 0; n < 4; ++n)
                    acc[m][n] = __builtin_amdgcn_mfma_f32_16x16x32_bf16(
                        af[m], bfv[n], acc[m][n], 0, 0, 0);
        }
        if (more) {
#pragma unroll
            for (int i = 0; i < 4; ++i) {
                const int c = i * 512 + t;
                __hip_bfloat16 tmp[8] __attribute__((aligned(16)));
                tmp[0] = __float2bfloat16(rA[i][0].x); tmp[1] = __float2bfloat16(rA[i][0].y);
                tmp[2] = __float2bfloat16(rA[i][0].z); tmp[3] = __float2bfloat16(rA[i][0].w);
                tmp[4] = __float2bfloat16(rA[i][1].x); tmp[5] = __float2bfloat16(rA[i][1].y);
                tmp[6] = __float2bfloat16(rA[i][1].z); tmp[7] = __float2bfloat16(rA[i][1].w);
                *(short8*)(void*)&sm[cur ^ 1][c * 8] = *(short8*)(void*)tmp;
            }
            __syncthreads();
        }
        cur ^= 1;
    }

    const long rowBase = (long)by * 256 + wm * 64;
    const int colBase = bx * 128 + wn * 64;
#pragma unroll
    for (int m = 0; m < 4; ++m) {
#pragma unroll
        for (int n = 0; n < 4; ++n) {
            const int col = colBase + n * 16 + fr;
            const float bv = bias[col];
#pragma unroll
            for (int j = 0; j < 4; ++j) {
                const long row = rowBase + m * 16 + quad * 4 + j;
                alpha[row * 256 + col] = __float2bfloat16(tanhf(acc[m][n][j] + bv));
            }
        }
    }
}

// -------- gemm_pv v3: r9 data layout + T4 counted-vmcnt deep pipeline ------
// Tile 256t x 128h x BK=32s, K=512, 8 waves (4x2), wave tile 64x64.
// A (P bf16): global_load_lds, TRIPLE-buffered (issued at k for k+2).
// B (X f32): reg-staged transposed (same mapping as r9), double-buffered LDS.
// Per step: issue A(k+2) -> compute(k) -> cvt+write B(k+1) -> load B(k+2)
//   -> sched_barrier -> s_waitcnt vmcnt(4) lgkmcnt(0) -> s_barrier.
// vmcnt(4): the 4 newest ops (A(k+2) glds x2 + B(k+2) loads x2) may stay in
// flight across the barrier; everything older (incl. A(k+1)) is forced done.
__global__ __launch_bounds__(512, 4) void gemm_pv_kernel(
    const __hip_bfloat16* __restrict__ P,  // [B*512][512]
    const float* __restrict__ Xf,          // [B*512][1024]
    float* __restrict__ Z) {               // [B*512][1024]
    __shared__ __align__(16) short smA[3][8192];   // 16KB x3
    __shared__ __align__(16) short smB[2][5120];   // 10KB x2

    int bx = blockIdx.x, by = blockIdx.y, bz = blockIdx.z;
    {   // T1 bijective XCD-chunked swizzle, nwg = 8*2*64 = 1024
        const int nx = gridDim.x, ny = gridDim.y;
        const int nwg = nx * ny * gridDim.z;
        const int lin = bx + nx * (by + ny * bz);
        const int swz = (lin & 7) * (nwg >> 3) + (lin >> 3);
        bx = swz % nx;
        const int r = swz / nx;
        by = r % ny;
        bz = r / ny;
    }

    const int t = threadIdx.x;
    const int w = t >> 6, lane = t & 63;
    const int wm = w >> 1, wn = w & 1;   // 4 x 2 waves
    const int fr = lane & 15, quad = lane >> 4;

    const __hip_bfloat16* Ab = P + ((long)bz * 512 + by * 256) * 512;
    const float* Bb = Xf + (long)bz * 512 * 1024 + bx * 128;

    // A staging slots (2 granules per thread) — identical mapping to r9
    int acb[2], arow[2], akc[2];
#pragma unroll
    for (int i = 0; i < 2; ++i) {
        acb[i] = i * 512 + w * 64;           // wave-uniform
        const int s = acb[i] + lane;
        arow[i] = s >> 2;
        akc[i] = ((s & 3) ^ ((arow[i] >> 1) & 3)) * 8;
    }
    // B thread mapping: s-pair (2bi, 2bi+1), h = bhc*4 + j — identical to r9
    const int bi = t & 15;
    const int bhc = t >> 4;   // 0..31

    f32x4 acc[4][4] = {};
    float4 r0, r1;

#define PV_ISSUE_A(KT, BUF)                                                     \
    _Pragma("unroll") for (int i = 0; i < 2; ++i)                               \
        __builtin_amdgcn_global_load_lds(                                       \
            (const void*)(Ab + (long)arow[i] * 512 + (KT) * 32 + akc[i]),       \
            (void*)(&smA[BUF][acb[i] * 8]), 16, 0, 0);

#define PV_LOAD_B(KT)                                                           \
    {                                                                           \
        const float* s0 = Bb + (long)((KT) * 32 + 2 * bi) * 1024 + bhc * 4;     \
        r0 = *(const float4*)(s0);                                              \
        r1 = *(const float4*)(s0 + 1024);                                       \
    }

#define PV_WRITE_B(BUF)                                                         \
    {                                                                           \
        int* dst = (int*)(void*)&smB[BUF][(bhc * 4) * 40 + bi * 2];             \
        _Pragma("unroll") for (int j = 0; j < 4; ++j) {                         \
            __hip_bfloat16 h0 = __float2bfloat16(((const float*)&r0)[j]);       \
            __hip_bfloat16 h1 = __float2bfloat16(((const float*)&r1)[j]);       \
            dst[j * 20] = (int)*(unsigned short*)&h0 |                          \
                          ((int)*(unsigned short*)&h1 << 16);                   \
        }                                                                       \
    }

    // ---- prologue: A(0)->buf0, A(1)->buf1, B(0) staged, B(1) in regs ----
    PV_ISSUE_A(0, 0)
    PV_ISSUE_A(1, 1)
    PV_LOAD_B(0)
    PV_WRITE_B(0)          // compiler auto-waits on B(0) regs
    PV_LOAD_B(1)
    __builtin_amdgcn_sched_barrier(0);
    asm volatile("s_waitcnt vmcnt(4)" ::: "memory");   // A(0) landed
    asm volatile("s_waitcnt lgkmcnt(0)" ::: "memory"); // B(0) LDS visible
    __builtin_amdgcn_s_barrier();
    __builtin_amdgcn_sched_barrier(0);

#pragma unroll
    for (int k = 0; k < 16; ++k) {
        if (k + 2 < 16) PV_ISSUE_A(k + 2, (k + 2) % 3)
        // ---- compute from smA[k%3], smB[k%2] ----
        {
            const short* At = &smA[k % 3][0];
            const short* Bt = &smB[k % 2][0];
            bf16x8 bfv[4];
#pragma unroll
            for (int n = 0; n < 4; ++n) {
                const int h = wn * 64 + n * 16 + fr;
                bfv[n] = *(const bf16x8*)(const void*)(Bt + h * 40 + quad * 8);
            }
#pragma unroll
            for (int m = 0; m < 4; ++m) {
                const int row = wm * 64 + m * 16 + fr;
                const int slot = row * 4 + (quad ^ ((row >> 1) & 3));
                const bf16x8 af = *(const bf16x8*)(const void*)(At + slot * 8);
#pragma unroll
                for (int n = 0; n < 4; ++n)
                    acc[m][n] = __builtin_amdgcn_mfma_f32_16x16x32_bf16(
                        af, bfv[n], acc[m][n], 0, 0, 0);
            }
        }
        if (k + 1 < 16) PV_WRITE_B((k + 1) % 2)   // auto-waits on B(k+1) regs
        if (k + 2 < 16) PV_LOAD_B(k + 2)
        __builtin_amdgcn_sched_barrier(0);
        if (k + 2 < 16) {
            asm volatile("s_waitcnt vmcnt(4)" ::: "memory");
        } else if (k + 1 < 16) {
            asm volatile("s_waitcnt vmcnt(0)" ::: "memory");
        }
        if (k + 1 < 16) {
            asm volatile("s_waitcnt lgkmcnt(0)" ::: "memory");
            __builtin_amdgcn_s_barrier();
            __builtin_amdgcn_sched_barrier(0);
        }
    }
#undef PV_ISSUE_A
#undef PV_LOAD_B
#undef PV_WRITE_B

    // epilogue: C/D layout col = lane&15, row = (lane>>4)*4 + j
    const long rowBase = (long)bz * 512 + by * 256 + wm * 64;
    const int colBase = bx * 128 + wn * 64;
#pragma unroll
    for (int m = 0; m < 4; ++m) {
#pragma unroll
        for (int n = 0; n < 4; ++n) {
            const int col = colBase + n * 16 + fr;
#pragma unroll
            for (int j = 0; j < 4; ++j) {
                const long row = rowBase + m * 16 + quad * 4 + j;
                Z[row * 1024 + col] = acc[m][n][j];
            }
        }
    }
}

// naive small transpose+convert: in [R][C] f32 -> out [C][R] bf16
__global__ __launch_bounds__(256) void transpose_cvt_kernel(const float* __restrict__ in,
                                                            __hip_bfloat16* __restrict__ out,
                                                            int R, int C) {
    const int o = blockIdx.x * 256 + threadIdx.x;
    if (o >= R * C) return;
    const int c = o / R;
    const int r = o - c * R;
    out[o] = __float2bfloat16(in[(long)r * C + c]);
}

// Fused scores+masked-softmax: per block, 64 query rows x full 512 key cols.
__global__ __launch_bounds__(512) void score_softmax_kernel(
    const __hip_bfloat16* __restrict__ Aa,  // alpha [32768][256]
    const __hip_bfloat16* __restrict__ Ut,  // [512][256]
    __hip_bfloat16* __restrict__ P,         // [32768][512]
    const int* __restrict__ sen) {
    __shared__ __align__(16) short At[64 * 64];
    __shared__ __align__(16) short Bts[512 * 64];
    __shared__ float red[2][64][9];

    const int t = threadIdx.x;
    const int w = t >> 6, lane = t & 63;
    const int fr = lane & 15, quad = lane >> 4;
    const long row0 = (long)blockIdx.x * 64;
    const __hip_bfloat16* Ab = Aa + row0 * 256;

    f32x4 acc[4][4] = {};

    for (int kt = 0; kt < 4; ++kt) {  // K = 256, BK = 64
        if (kt) __syncthreads();
        {
            const int cb = w * 64;
            const int c = cb + lane;
            const int row = c >> 3, kc = (c & 7) ^ (row & 7);
            __builtin_amdgcn_global_load_lds(
                (const void*)(Ab + (long)row * 256 + kt * 64 + kc * 8),
                (void*)(At + cb * 8), 16, 0, 0);
        }
#pragma unroll
        for (int i = 0; i < 8; ++i) {
            const int cb = i * 512 + w * 64;
            const int c = cb + lane;
            const int row = c >> 3, kc = (c & 7) ^ (row & 7);
            __builtin_amdgcn_global_load_lds(
                (const void*)(Ut + (long)row * 256 + kt * 64 + kc * 8),
                (void*)(Bts + cb * 8), 16, 0, 0);
        }
        __syncthreads();
#pragma unroll
        for (int ks = 0; ks < 2; ++ks) {
            bf16x8 af[4], bfv[4];
            const int kc = ks * 4 + quad;
#pragma unroll
            for (int m = 0; m < 4; ++m) {
                const int row = m * 16 + fr;
                const int chunk = row * 8 + (kc ^ (row & 7));
                af[m] = *(const bf16x8*)(const void*)(At + chunk * 8);
            }
#pragma unroll
            for (int n = 0; n < 4; ++n) {
                const int row = w * 64 + n * 16 + fr;
                const int chunk = row * 8 + (kc ^ (row & 7));
                bfv[n] = *(const bf16x8*)(const void*)(Bts + chunk * 8);
            }
#pragma unroll
            for (int m = 0; m < 4; ++m)
#pragma unroll
                for (int n = 0; n < 4; ++n)
                    acc[m][n] = __builtin_amdgcn_mfma_f32_16x16x32_bf16(
                        af[m], bfv[n], acc[m][n], 0, 0, 0);
        }
    }
    __syncthreads();

    const int L = sen[row0 >> 9];
    bool valid[4];
#pragma unroll
    for (int n = 0; n < 4; ++n) valid[n] = (w * 64 + n * 16 + fr) < L;

    float mx[4][4];
#pragma unroll
    for (int m = 0; m < 4; ++m)
#pragma unroll
        for (int j = 0; j < 4; ++j) {
            float v = -3.0e38f;
#pragma unroll
            for (int n = 0; n < 4; ++n)
                if (valid[n]) v = fmaxf(v, acc[m][n][j]);
#pragma unroll
            for (int off = 8; off >= 1; off >>= 1) v = fmaxf(v, __shfl_xor(v, off, 64));
            mx[m][j] = v;
        }
    if (fr == 0) {
#pragma unroll
        for (int m = 0; m < 4; ++m)
#pragma unroll
            for (int j = 0; j < 4; ++j) red[0][m * 16 + quad * 4 + j][w] = mx[m][j];
    }
    __syncthreads();
    float rmax[4][4];
#pragma unroll
    for (int m = 0; m < 4; ++m)
#pragma unroll
        for (int j = 0; j < 4; ++j) {
            const int row = m * 16 + quad * 4 + j;
            float v = red[0][row][0];
#pragma unroll
            for (int ww = 1; ww < 8; ++ww) v = fmaxf(v, red[0][row][ww]);
            rmax[m][j] = v;
        }

    float sum[4][4];
#pragma unroll
    for (int m = 0; m < 4; ++m)
#pragma unroll
        for (int j = 0; j < 4; ++j) {
            float s = 0.f;
#pragma unroll
            for (int n = 0; n < 4; ++n) {
                float e = valid[n] ? __expf(acc[m][n][j] - rmax[m][j]) : 0.f;
                acc[m][n][j] = e;
                s += e;
            }
#pragma unroll
            for (int off = 8; off >= 1; off >>= 1) s += __shfl_xor(s, off, 64);
            sum[m][j] = s;
        }
    if (fr == 0) {
#pragma unroll
        for (int m = 0; m < 4; ++m)
#pragma unroll
            for (int j = 0; j < 4; ++j) red[1][m * 16 + quad * 4 + j][w] = sum[m][j];
    }
    __syncthreads();
#pragma unroll
    for (int m = 0; m < 4; ++m)
#pragma unroll
        for (int j = 0; j < 4; ++j) {
            const int row = m * 16 + quad * 4 + j;
            float s = 0.f;
#pragma unroll
            for (int ww = 0; ww < 8; ++ww) s += red[1][row][ww];
            const float inv = 1.f / s;
#pragma unroll
            for (int n = 0; n < 4; ++n)
                P[(row0 + row) * 512 + w * 64 + n * 16 + fr] =
                    __float2bfloat16(acc[m][n][j] * inv);
        }
}

extern "C" void kernel_launch(void* const* d_in, const int* in_sizes, int n_in,
                              void* d_out, int out_size, void* d_ws, size_t ws_size,
                              hipStream_t stream) {
    const float* X = (const float*)d_in[0];
    const int* sen = (const int*)d_in[1];
    const float* W = (const float*)d_in[2];
    const float* bias = (const float*)d_in[3];
    const float* U = (const float*)d_in[4];
    float* out = (float*)d_out;

    const int B = 64, T = 512, H = 1024, A = 256;
    const long M = (long)B * T;  // 32768

    // workspace: P (32Mi) | Wt (0.5Mi) | Ut (0.25Mi)
    char* ws = (char*)d_ws;
    __hip_bfloat16* Pbf = (__hip_bfloat16*)ws;
    __hip_bfloat16* Wt = (__hip_bfloat16*)(ws + M * T * 2);
    __hip_bfloat16* Ut = (__hip_bfloat16*)((char*)Wt + (long)H * A * 2);

    // d_out scratch: alpha bf16 at [64Mi,80Mi) — consumed by score_softmax
    // before gemm_pv overwrites all of d_out with Z.
    __hip_bfloat16* alpha = (__hip_bfloat16*)((char*)d_out + M * H * 2);

    // 1. W^T [A][H], U^T [T][A]
    transpose_cvt_kernel<<<(H * A) / 256, 256, 0, stream>>>(W, Wt, H, A);
    transpose_cvt_kernel<<<(A * T) / 256, 256, 0, stream>>>(U, Ut, A, T);
    // 2. alpha = tanh(X*W + b), A-side reg-staged from f32 X, 256 wgs
    gemm_xw_kernel<<<dim3(2, 128), 512, 0, stream>>>(X, Wt, alpha, bias);
    // 3. P = softmax(alpha * U^T, mask) fused, bf16
    score_softmax_kernel<<<(int)(M / 64), 512, 0, stream>>>(alpha, Ut, Pbf, sen);
    // 4. Z = P * X — counted-vmcnt deep pipeline (T4), depth-2 prefetch
    gemm_pv_kernel<<<dim3(H / 128, T / 256, B), 512, 0, stream>>>(Pbf, X, out);
}

// Round 11
// 139.426 us; speedup vs baseline: 1.3099x; 1.0335x over previous
//
#include <hip/hip_runtime.h>
#include <hip/hip_bf16.h>

typedef short short8 __attribute__((ext_vector_type(8)));
typedef short short4v __attribute__((ext_vector_type(4)));
typedef float f32x4 __attribute__((ext_vector_type(4)));
typedef __bf16 bf16x8 __attribute__((ext_vector_type(8)));

// ---- stage a ROWSx64 bf16 tile via global_load_lds, 16B-chunk XOR swizzle --
template <int ROWS>
__device__ __forceinline__ void stage2(const __hip_bfloat16* __restrict__ g,
                                       int ld, short* lds, int t) {
    const int w = t >> 6;
    const int lane = t & 63;
#pragma unroll
    for (int i = 0; i < ROWS / 64; ++i) {
        const int cb = i * 512 + w * 64;     // wave-uniform chunk base
        const int c = cb + lane;
        const int row = c >> 3;
        const int kc = (c & 7) ^ (row & 7);
        __builtin_amdgcn_global_load_lds((const void*)(g + (long)row * ld + kc * 8),
                                         (void*)(lds + cb * 8), 16, 0, 0);
    }
}

// -------- gemm_xw v2: alpha = tanh(X_f32 * Wt^T + b), T4 deep pipeline -----
// BM=128(t) x BN=128(a) x BK=64(h), K=1024 -> 16 steps. Grid (2,256)=512 wgs.
// 512 thr = 8 waves (4wm x 2wn), wave tile 32x64: acc 2x4 f32x4 = 32 regs.
// B (Wt bf16): global_load_lds, TRIPLE-buffered (issued at k for k+2).
// A (X f32): reg-staged (4 float4/thread), cvt->ds_write, double-buffered.
// Counted vmcnt(6) = B glds(k+2) x2 + A reg-loads(k+2) x4 stay in flight.
// LDS 3*16 + 2*16 = 80KB -> 2 blocks/CU.
__global__ __launch_bounds__(512, 4) void gemm_xw_kernel(
    const float* __restrict__ Xf,           // [32768][1024]
    const __hip_bfloat16* __restrict__ Wt,  // [256][1024]
    __hip_bfloat16* __restrict__ alpha,     // [32768][256]
    const float* __restrict__ bias) {
    __shared__ __align__(16) short smB[3][8192];   // 16KB x3 (Wt tiles)
    __shared__ __align__(16) short smA[2][8192];   // 16KB x2 (X tiles, bf16)

    int bx = blockIdx.x, by = blockIdx.y;
    {   // T1 swizzle, nwg = 512
        const int nx = gridDim.x, ny = gridDim.y;
        const int nwg = nx * ny;
        const int lin = bx + nx * by;
        const int swz = (lin & 7) * (nwg >> 3) + (lin >> 3);
        bx = swz % nx;
        by = swz / nx;
    }

    const int t = threadIdx.x;
    const int w = t >> 6, lane = t & 63;
    const int wm = w >> 1, wn = w & 1;   // 4 x 2 waves
    const int fr = lane & 15, quad = lane >> 4;

    const float* Ab = Xf + (long)by * 128 * 1024;
    const __hip_bfloat16* Bb = Wt + (long)bx * 128 * 1024;

    // A granule mapping: granule c holds (row=c>>3, h-chunk kc=(c&7)^(row&7))
    int acs[2], arow[2], akc[2];
#pragma unroll
    for (int i = 0; i < 2; ++i) {
        acs[i] = i * 512 + t;
        arow[i] = acs[i] >> 3;
        akc[i] = ((acs[i] & 7) ^ (arow[i] & 7)) * 8;
    }

    f32x4 acc[2][4] = {};
    float4 rA[2][2];

#define XW_ISSUE_B(KT, BUF) stage2<128>(Bb + (KT) * 64, 1024, &smB[BUF][0], t);

#define XW_LOAD_A(KT)                                                           \
    _Pragma("unroll") for (int i = 0; i < 2; ++i) {                             \
        const float* src = Ab + (long)arow[i] * 1024 + (KT) * 64 + akc[i];      \
        rA[i][0] = *(const float4*)(src);                                       \
        rA[i][1] = *(const float4*)(src + 4);                                   \
    }

#define XW_WRITE_A(BUF)                                                         \
    _Pragma("unroll") for (int i = 0; i < 2; ++i) {                             \
        __hip_bfloat16 tmp[8] __attribute__((aligned(16)));                     \
        tmp[0] = __float2bfloat16(rA[i][0].x);                                  \
        tmp[1] = __float2bfloat16(rA[i][0].y);                                  \
        tmp[2] = __float2bfloat16(rA[i][0].z);                                  \
        tmp[3] = __float2bfloat16(rA[i][0].w);                                  \
        tmp[4] = __float2bfloat16(rA[i][1].x);                                  \
        tmp[5] = __float2bfloat16(rA[i][1].y);                                  \
        tmp[6] = __float2bfloat16(rA[i][1].z);                                  \
        tmp[7] = __float2bfloat16(rA[i][1].w);                                  \
        *(short8*)(void*)&smA[BUF][acs[i] * 8] = *(short8*)(void*)tmp;          \
    }

    // ---- prologue: B(0)->buf0, B(1)->buf1, A(0) staged, A(1) in regs ----
    XW_ISSUE_B(0, 0)
    XW_ISSUE_B(1, 1)
    XW_LOAD_A(0)
    XW_WRITE_A(0)          // compiler auto-waits on A(0) regs (drains B glds too)
    XW_LOAD_A(1)
    __builtin_amdgcn_sched_barrier(0);
    asm volatile("s_waitcnt vmcnt(4)" ::: "memory");
    asm volatile("s_waitcnt lgkmcnt(0)" ::: "memory");
    __builtin_amdgcn_s_barrier();
    __builtin_amdgcn_sched_barrier(0);

#pragma unroll
    for (int k = 0; k < 16; ++k) {
        if (k + 2 < 16) XW_ISSUE_B(k + 2, (k + 2) % 3)
        // ---- compute from smB[k%3], smA[k%2] ----
        {
            const short* At = &smA[k % 2][0];
            const short* Bt = &smB[k % 3][0];
#pragma unroll
            for (int ks = 0; ks < 2; ++ks) {
                bf16x8 af[2], bfv[4];
                const int kc = ks * 4 + quad;
#pragma unroll
                for (int m = 0; m < 2; ++m) {
                    const int row = wm * 32 + m * 16 + fr;
                    const int chunk = row * 8 + (kc ^ (row & 7));
                    af[m] = *(const bf16x8*)(const void*)(At + chunk * 8);
                }
#pragma unroll
                for (int n = 0; n < 4; ++n) {
                    const int row = wn * 64 + n * 16 + fr;
                    const int chunk = row * 8 + (kc ^ (row & 7));
                    bfv[n] = *(const bf16x8*)(const void*)(Bt + chunk * 8);
                }
#pragma unroll
                for (int m = 0; m < 2; ++m)
#pragma unroll
                    for (int n = 0; n < 4; ++n)
                        acc[m][n] = __builtin_amdgcn_mfma_f32_16x16x32_bf16(
                            af[m], bfv[n], acc[m][n], 0, 0, 0);
            }
        }
        if (k + 1 < 16) XW_WRITE_A((k + 1) % 2)   // auto-waits on A(k+1) regs
        if (k + 2 < 16) XW_LOAD_A(k + 2)
        __builtin_amdgcn_sched_barrier(0);
        if (k + 2 < 16) {
            asm volatile("s_waitcnt vmcnt(6)" ::: "memory");
        } else if (k + 1 < 16) {
            asm volatile("s_waitcnt vmcnt(0)" ::: "memory");
        }
        if (k + 1 < 16) {
            asm volatile("s_waitcnt lgkmcnt(0)" ::: "memory");
            __builtin_amdgcn_s_barrier();
            __builtin_amdgcn_sched_barrier(0);
        }
    }
#undef XW_ISSUE_B
#undef XW_LOAD_A
#undef XW_WRITE_A

    const long rowBase = (long)by * 128 + wm * 32;
    const int colBase = bx * 128 + wn * 64;
#pragma unroll
    for (int m = 0; m < 2; ++m) {
#pragma unroll
        for (int n = 0; n < 4; ++n) {
            const int col = colBase + n * 16 + fr;
            const float bv = bias[col];
#pragma unroll
            for (int j = 0; j < 4; ++j) {
                const long row = rowBase + m * 16 + quad * 4 + j;
                alpha[row * 256 + col] = __float2bfloat16(tanhf(acc[m][n][j] + bv));
            }
        }
    }
}

// -------- gemm_pv v3: r9 data layout + T4 counted-vmcnt deep pipeline ------
// (unchanged from r10 — validated at ~<45 us)
__global__ __launch_bounds__(512, 4) void gemm_pv_kernel(
    const __hip_bfloat16* __restrict__ P,  // [B*512][512]
    const float* __restrict__ Xf,          // [B*512][1024]
    float* __restrict__ Z) {               // [B*512][1024]
    __shared__ __align__(16) short smA[3][8192];   // 16KB x3
    __shared__ __align__(16) short smB[2][5120];   // 10KB x2

    int bx = blockIdx.x, by = blockIdx.y, bz = blockIdx.z;
    {   // T1 bijective XCD-chunked swizzle, nwg = 8*2*64 = 1024
        const int nx = gridDim.x, ny = gridDim.y;
        const int nwg = nx * ny * gridDim.z;
        const int lin = bx + nx * (by + ny * bz);
        const int swz = (lin & 7) * (nwg >> 3) + (lin >> 3);
        bx = swz % nx;
        const int r = swz / nx;
        by = r % ny;
        bz = r / ny;
    }

    const int t = threadIdx.x;
    const int w = t >> 6, lane = t & 63;
    const int wm = w >> 1, wn = w & 1;   // 4 x 2 waves
    const int fr = lane & 15, quad = lane >> 4;

    const __hip_bfloat16* Ab = P + ((long)bz * 512 + by * 256) * 512;
    const float* Bb = Xf + (long)bz * 512 * 1024 + bx * 128;

    int acb[2], arow[2], akc[2];
#pragma unroll
    for (int i = 0; i < 2; ++i) {
        acb[i] = i * 512 + w * 64;           // wave-uniform
        const int s = acb[i] + lane;
        arow[i] = s >> 2;
        akc[i] = ((s & 3) ^ ((arow[i] >> 1) & 3)) * 8;
    }
    const int bi = t & 15;
    const int bhc = t >> 4;   // 0..31

    f32x4 acc[4][4] = {};
    float4 r0, r1;

#define PV_ISSUE_A(KT, BUF)                                                     \
    _Pragma("unroll") for (int i = 0; i < 2; ++i)                               \
        __builtin_amdgcn_global_load_lds(                                       \
            (const void*)(Ab + (long)arow[i] * 512 + (KT) * 32 + akc[i]),       \
            (void*)(&smA[BUF][acb[i] * 8]), 16, 0, 0);

#define PV_LOAD_B(KT)                                                           \
    {                                                                           \
        const float* s0 = Bb + (long)((KT) * 32 + 2 * bi) * 1024 + bhc * 4;     \
        r0 = *(const float4*)(s0);                                              \
        r1 = *(const float4*)(s0 + 1024);                                       \
    }

#define PV_WRITE_B(BUF)                                                         \
    {                                                                           \
        int* dst = (int*)(void*)&smB[BUF][(bhc * 4) * 40 + bi * 2];             \
        _Pragma("unroll") for (int j = 0; j < 4; ++j) {                         \
            __hip_bfloat16 h0 = __float2bfloat16(((const float*)&r0)[j]);       \
            __hip_bfloat16 h1 = __float2bfloat16(((const float*)&r1)[j]);       \
            dst[j * 20] = (int)*(unsigned short*)&h0 |                          \
                          ((int)*(unsigned short*)&h1 << 16);                   \
        }                                                                       \
    }

    PV_ISSUE_A(0, 0)
    PV_ISSUE_A(1, 1)
    PV_LOAD_B(0)
    PV_WRITE_B(0)
    PV_LOAD_B(1)
    __builtin_amdgcn_sched_barrier(0);
    asm volatile("s_waitcnt vmcnt(4)" ::: "memory");
    asm volatile("s_waitcnt lgkmcnt(0)" ::: "memory");
    __builtin_amdgcn_s_barrier();
    __builtin_amdgcn_sched_barrier(0);

#pragma unroll
    for (int k = 0; k < 16; ++k) {
        if (k + 2 < 16) PV_ISSUE_A(k + 2, (k + 2) % 3)
        {
            const short* At = &smA[k % 3][0];
            const short* Bt = &smB[k % 2][0];
            bf16x8 bfv[4];
#pragma unroll
            for (int n = 0; n < 4; ++n) {
                const int h = wn * 64 + n * 16 + fr;
                bfv[n] = *(const bf16x8*)(const void*)(Bt + h * 40 + quad * 8);
            }
#pragma unroll
            for (int m = 0; m < 4; ++m) {
                const int row = wm * 64 + m * 16 + fr;
                const int slot = row * 4 + (quad ^ ((row >> 1) & 3));
                const bf16x8 af = *(const bf16x8*)(const void*)(At + slot * 8);
#pragma unroll
                for (int n = 0; n < 4; ++n)
                    acc[m][n] = __builtin_amdgcn_mfma_f32_16x16x32_bf16(
                        af, bfv[n], acc[m][n], 0, 0, 0);
            }
        }
        if (k + 1 < 16) PV_WRITE_B((k + 1) % 2)
        if (k + 2 < 16) PV_LOAD_B(k + 2)
        __builtin_amdgcn_sched_barrier(0);
        if (k + 2 < 16) {
            asm volatile("s_waitcnt vmcnt(4)" ::: "memory");
        } else if (k + 1 < 16) {
            asm volatile("s_waitcnt vmcnt(0)" ::: "memory");
        }
        if (k + 1 < 16) {
            asm volatile("s_waitcnt lgkmcnt(0)" ::: "memory");
            __builtin_amdgcn_s_barrier();
            __builtin_amdgcn_sched_barrier(0);
        }
    }
#undef PV_ISSUE_A
#undef PV_LOAD_B
#undef PV_WRITE_B

    const long rowBase = (long)bz * 512 + by * 256 + wm * 64;
    const int colBase = bx * 128 + wn * 64;
#pragma unroll
    for (int m = 0; m < 4; ++m) {
#pragma unroll
        for (int n = 0; n < 4; ++n) {
            const int col = colBase + n * 16 + fr;
#pragma unroll
            for (int j = 0; j < 4; ++j) {
                const long row = rowBase + m * 16 + quad * 4 + j;
                Z[row * 1024 + col] = acc[m][n][j];
            }
        }
    }
}

// naive small transpose+convert: in [R][C] f32 -> out [C][R] bf16
__global__ __launch_bounds__(256) void transpose_cvt_kernel(const float* __restrict__ in,
                                                            __hip_bfloat16* __restrict__ out,
                                                            int R, int C) {
    const int o = blockIdx.x * 256 + threadIdx.x;
    if (o >= R * C) return;
    const int c = o / R;
    const int r = o - c * R;
    out[o] = __float2bfloat16(in[(long)r * C + c]);
}

// Fused scores+masked-softmax: per block, 64 query rows x full 512 key cols.
__global__ __launch_bounds__(512) void score_softmax_kernel(
    const __hip_bfloat16* __restrict__ Aa,  // alpha [32768][256]
    const __hip_bfloat16* __restrict__ Ut,  // [512][256]
    __hip_bfloat16* __restrict__ P,         // [32768][512]
    const int* __restrict__ sen) {
    __shared__ __align__(16) short At[64 * 64];
    __shared__ __align__(16) short Bts[512 * 64];
    __shared__ float red[2][64][9];

    const int t = threadIdx.x;
    const int w = t >> 6, lane = t & 63;
    const int fr = lane & 15, quad = lane >> 4;
    const long row0 = (long)blockIdx.x * 64;
    const __hip_bfloat16* Ab = Aa + row0 * 256;

    f32x4 acc[4][4] = {};

    for (int kt = 0; kt < 4; ++kt) {  // K = 256, BK = 64
        if (kt) __syncthreads();
        {
            const int cb = w * 64;
            const int c = cb + lane;
            const int row = c >> 3, kc = (c & 7) ^ (row & 7);
            __builtin_amdgcn_global_load_lds(
                (const void*)(Ab + (long)row * 256 + kt * 64 + kc * 8),
                (void*)(At + cb * 8), 16, 0, 0);
        }
#pragma unroll
        for (int i = 0; i < 8; ++i) {
            const int cb = i * 512 + w * 64;
            const int c = cb + lane;
            const int row = c >> 3, kc = (c & 7) ^ (row & 7);
            __builtin_amdgcn_global_load_lds(
                (const void*)(Ut + (long)row * 256 + kt * 64 + kc * 8),
                (void*)(Bts + cb * 8), 16, 0, 0);
        }
        __syncthreads();
#pragma unroll
        for (int ks = 0; ks < 2; ++ks) {
            bf16x8 af[4], bfv[4];
            const int kc = ks * 4 + quad;
#pragma unroll
            for (int m = 0; m < 4; ++m) {
                const int row = m * 16 + fr;
                const int chunk = row * 8 + (kc ^ (row & 7));
                af[m] = *(const bf16x8*)(const void*)(At + chunk * 8);
            }
#pragma unroll
            for (int n = 0; n < 4; ++n) {
                const int row = w * 64 + n * 16 + fr;
                const int chunk = row * 8 + (kc ^ (row & 7));
                bfv[n] = *(const bf16x8*)(const void*)(Bts + chunk * 8);
            }
#pragma unroll
            for (int m = 0; m < 4; ++m)
#pragma unroll
                for (int n = 0; n < 4; ++n)
                    acc[m][n] = __builtin_amdgcn_mfma_f32_16x16x32_bf16(
                        af[m], bfv[n], acc[m][n], 0, 0, 0);
        }
    }
    __syncthreads();

    const int L = sen[row0 >> 9];
    bool valid[4];
#pragma unroll
    for (int n = 0; n < 4; ++n) valid[n] = (w * 64 + n * 16 + fr) < L;

    float mx[4][4];
#pragma unroll
    for (int m = 0; m < 4; ++m)
#pragma unroll
        for (int j = 0; j < 4; ++j) {
            float v = -3.0e38f;
#pragma unroll
            for (int n = 0; n < 4; ++n)
                if (valid[n]) v = fmaxf(v, acc[m][n][j]);
#pragma unroll
            for (int off = 8; off >= 1; off >>= 1) v = fmaxf(v, __shfl_xor(v, off, 64));
            mx[m][j] = v;
        }
    if (fr == 0) {
#pragma unroll
        for (int m = 0; m < 4; ++m)
#pragma unroll
            for (int j = 0; j < 4; ++j) red[0][m * 16 + quad * 4 + j][w] = mx[m][j];
    }
    __syncthreads();
    float rmax[4][4];
#pragma unroll
    for (int m = 0; m < 4; ++m)
#pragma unroll
        for (int j = 0; j < 4; ++j) {
            const int row = m * 16 + quad * 4 + j;
            float v = red[0][row][0];
#pragma unroll
            for (int ww = 1; ww < 8; ++ww) v = fmaxf(v, red[0][row][ww]);
            rmax[m][j] = v;
        }

    float sum[4][4];
#pragma unroll
    for (int m = 0; m < 4; ++m)
#pragma unroll
        for (int j = 0; j < 4; ++j) {
            float s = 0.f;
#pragma unroll
            for (int n = 0; n < 4; ++n) {
                float e = valid[n] ? __expf(acc[m][n][j] - rmax[m][j]) : 0.f;
                acc[m][n][j] = e;
                s += e;
            }
#pragma unroll
            for (int off = 8; off >= 1; off >>= 1) s += __shfl_xor(s, off, 64);
            sum[m][j] = s;
        }
    if (fr == 0) {
#pragma unroll
        for (int m = 0; m < 4; ++m)
#pragma unroll
            for (int j = 0; j < 4; ++j) red[1][m * 16 + quad * 4 + j][w] = sum[m][j];
    }
    __syncthreads();
#pragma unroll
    for (int m = 0; m < 4; ++m)
#pragma unroll
        for (int j = 0; j < 4; ++j) {
            const int row = m * 16 + quad * 4 + j;
            float s = 0.f;
#pragma unroll
            for (int ww = 0; ww < 8; ++ww) s += red[1][row][ww];
            const float inv = 1.f / s;
#pragma unroll
            for (int n = 0; n < 4; ++n)
                P[(row0 + row) * 512 + w * 64 + n * 16 + fr] =
                    __float2bfloat16(acc[m][n][j] * inv);
        }
}

extern "C" void kernel_launch(void* const* d_in, const int* in_sizes, int n_in,
                              void* d_out, int out_size, void* d_ws, size_t ws_size,
                              hipStream_t stream) {
    const float* X = (const float*)d_in[0];
    const int* sen = (const int*)d_in[1];
    const float* W = (const float*)d_in[2];
    const float* bias = (const float*)d_in[3];
    const float* U = (const float*)d_in[4];
    float* out = (float*)d_out;

    const int B = 64, T = 512, H = 1024, A = 256;
    const long M = (long)B * T;  // 32768

    // workspace: P (32Mi) | Wt (0.5Mi) | Ut (0.25Mi)
    char* ws = (char*)d_ws;
    __hip_bfloat16* Pbf = (__hip_bfloat16*)ws;
    __hip_bfloat16* Wt = (__hip_bfloat16*)(ws + M * T * 2);
    __hip_bfloat16* Ut = (__hip_bfloat16*)((char*)Wt + (long)H * A * 2);

    // d_out scratch: alpha bf16 at [64Mi,80Mi) — consumed by score_softmax
    // before gemm_pv overwrites all of d_out with Z.
    __hip_bfloat16* alpha = (__hip_bfloat16*)((char*)d_out + M * H * 2);

    // 1. W^T [A][H], U^T [T][A]
    transpose_cvt_kernel<<<(H * A) / 256, 256, 0, stream>>>(W, Wt, H, A);
    transpose_cvt_kernel<<<(A * T) / 256, 256, 0, stream>>>(U, Ut, A, T);
    // 2. alpha = tanh(X*W + b) — T4 deep pipeline, 512 wgs, 2 blocks/CU
    gemm_xw_kernel<<<dim3(2, 256), 512, 0, stream>>>(X, Wt, alpha, bias);
    // 3. P = softmax(alpha * U^T, mask) fused, bf16
    score_softmax_kernel<<<(int)(M / 64), 512, 0, stream>>>(alpha, Ut, Pbf, sen);
    // 4. Z = P * X — counted-vmcnt deep pipeline (T4), depth-2 prefetch
    gemm_pv_kernel<<<dim3(H / 128, T / 256, B), 512, 0, stream>>>(Pbf, X, out);
}